// Round 5
// baseline (220.120 us; speedup 1.0000x reference)
//
#include <hip/hip_runtime.h>
#include <hip/hip_bf16.h>
#include <stdint.h>

// Problem constants
// B=128 STREAM=512 IN_CH=4 EXTRA=5 GROUPS=2 DEPTH=3 STEP=16 LENGTH=32 RNN=256 OUT=10
// C=10 SIG_C=1110 W=31 F=2220, padded K = 2240, GEMM M = 31*128 = 3968, N = 768
// gi layout (f16, COALESCED): chunk u of thread gtid at step (t,bb):
//   f16 offset = ((t*8+bb)*6 + u)*2048 + gtid*4,  u = gs*2+gtc in [0,6)
// gi VALUES pre-scaled for exp2-based gate math:
//   r,z chunks: -log2e*(gemm + b_ih + b_hh);  n chunks: 2*log2e*(gemm + b_ih)
// FUSED K2+K3: blocks [0,192) gemm role (186 live), blocks [192,200) gru role.
//   gemm blocks release via done-counter (threadfence+syncthreads+atomicAdd);
//   gru blocks spin once up-front (all blocks co-resident: 194 <= 256 CUs).
// GEMM role: 8 waves, 128x128 tile, 7-LDS-buffer 6-deep global_load_lds pipeline.
// GRU role: W_hh pinned in AGPRs a[0:127] (fp8 rz + f16 n); accs in VGPRs.

typedef _Float16 f16;
typedef f16  f16x2 __attribute__((ext_vector_type(2)));
typedef f16  f16x4 __attribute__((ext_vector_type(4)));
typedef f16  f16x8 __attribute__((ext_vector_type(8)));
typedef float f32x2 __attribute__((ext_vector_type(2)));
typedef float f32x4 __attribute__((ext_vector_type(4)));

#define ASYNC16(gp, lp) __builtin_amdgcn_global_load_lds( \
    (const __attribute__((address_space(1))) void*)(gp),  \
    (__attribute__((address_space(3))) void*)(lp), 16, 0, 0)

#define BAR_LDS() do { asm volatile("s_waitcnt lgkmcnt(0)" ::: "memory"); \
                       __builtin_amdgcn_s_barrier();                      \
                       asm volatile("" ::: "memory"); } while (0)

__device__ __forceinline__ float fexp2(float x) {
    float r; asm("v_exp_f32 %0, %1" : "=v"(r) : "v"(x)); return r;
}
__device__ __forceinline__ float frcp(float x) {
    float r; asm("v_rcp_f32 %0, %1" : "=v"(r) : "v"(x)); return r;
}

// ---------------------------------------------------------------- K0: prep
// blocks [0,840):    W_ih f32 -> f16 (pad 2220->2240), 8 elems/thread
// blocks [840,936):  W_hh f32 -> f16 (all) + fp8*16 (r,z rows); block 840 zeroes done
// blocks [936,2920): signature chains, 4 per block (register-resident inner loop)
__global__ __launch_bounds__(256) void prep_kernel(const float* __restrict__ x,
                                                   const float* __restrict__ W_aug,
                                                   const float* __restrict__ Wih,
                                                   const float* __restrict__ Whh,
                                                   f16* __restrict__ sig16,
                                                   f16* __restrict__ wih16,
                                                   f16* __restrict__ whh16,
                                                   uint8_t* __restrict__ whh8,
                                                   unsigned int* __restrict__ done) {
    __shared__ float dxs[4][31][10];
    const int tid = threadIdx.x;
    if (blockIdx.x < 840) {
        int c = blockIdx.x * 256 + tid;          // chunk 0..215039
        int r = c / 280, kc = (c - r * 280) * 8;
        const float* src = Wih + (size_t)r * 2220 + kc;
        f16x8 o;
        if (kc + 8 <= 2220) {
            float4 v0 = *(const float4*)(src);
            float4 v1 = *(const float4*)(src + 4);
            o[0]=(f16)v0.x; o[1]=(f16)v0.y; o[2]=(f16)v0.z; o[3]=(f16)v0.w;
            o[4]=(f16)v1.x; o[5]=(f16)v1.y; o[6]=(f16)v1.z; o[7]=(f16)v1.w;
        } else {
#pragma unroll
            for (int j = 0; j < 8; j++)
                o[j] = (f16)((kc + j < 2220) ? src[j] : 0.0f);
        }
        *(f16x8*)(wih16 + (size_t)r * 2240 + kc) = o;
        return;
    }
    if (blockIdx.x < 936) {
        if (blockIdx.x == 840 && tid == 0) *done = 0u;   // reset release counter
        int c2 = ((int)blockIdx.x - 840) * 256 + tid;    // 0..24575
        int j8 = c2 * 8;
        float w[8];
        {
            float4 v0 = *(const float4*)(Whh + j8);
            float4 v1 = *(const float4*)(Whh + j8 + 4);
            w[0]=v0.x; w[1]=v0.y; w[2]=v0.z; w[3]=v0.w;
            w[4]=v1.x; w[5]=v1.y; w[6]=v1.z; w[7]=v1.w;
        }
        f16x8 o;
#pragma unroll
        for (int j = 0; j < 8; j++) o[j] = (f16)w[j];
        *(f16x8*)(whh16 + j8) = o;
        if (j8 < 131072) {                       // r,z gate rows -> fp8 e4m3 (x16)
            uint32_t p01 = (uint32_t)__builtin_amdgcn_cvt_pk_fp8_f32(w[0]*16.f, w[1]*16.f, 0, false) & 0xffffu;
            uint32_t p23 = (uint32_t)__builtin_amdgcn_cvt_pk_fp8_f32(w[2]*16.f, w[3]*16.f, 0, false) & 0xffffu;
            uint32_t p45 = (uint32_t)__builtin_amdgcn_cvt_pk_fp8_f32(w[4]*16.f, w[5]*16.f, 0, false) & 0xffffu;
            uint32_t p67 = (uint32_t)__builtin_amdgcn_cvt_pk_fp8_f32(w[6]*16.f, w[7]*16.f, 0, false) & 0xffffu;
            uint2 st = make_uint2(p01 | (p23 << 16), p45 | (p67 << 16));
            *(uint2*)(whh8 + j8) = st;
        }
        return;
    }
    // ---- signature chains (block-uniform branch; __syncthreads safe)
    const int sub = tid >> 6, t64 = tid & 63;
    const int cid = ((int)blockIdx.x - 936) * 4 + sub;   // 0..7935
    const int w = cid % 31;
    const int bg = cid / 31;
    const int b = bg >> 1, g = bg & 1;
    if (t64 < 31) {
        int s = w * 16 + t64;
        const float4 x0 = *(const float4*)(x + ((size_t)b * 512 + s) * 4);
        const float4 x1 = *(const float4*)(x + ((size_t)b * 512 + s + 1) * 4);
        float d0 = x1.x - x0.x, d1 = x1.y - x0.y, d2 = x1.z - x0.z, d3 = x1.w - x0.w;
        dxs[sub][t64][0] = d0; dxs[sub][t64][1] = d1;
        dxs[sub][t64][2] = d2; dxs[sub][t64][3] = d3;
        dxs[sub][t64][4] = 1.0f / 511.0f;
#pragma unroll
        for (int e = 0; e < 5; e++) {
            const float* wa = W_aug + (g * 5 + e) * 4;
            dxs[sub][t64][5 + e] = d0 * wa[0] + d1 * wa[1] + d2 * wa[2] + d3 * wa[3];
        }
    }
    __syncthreads();
    size_t base = ((size_t)(w * 128 + b)) * 2240 + (size_t)g * 1110;
    if (t64 < 50) {
        int p0 = 2 * t64, p1 = p0 + 1;
        int i0 = p0 / 10, j0 = p0 % 10, j1 = j0 + 1;   // p0 even -> j1 <= 9
        // loop-invariant LDS pointers: dynamic column index resolved ONCE
        const float* dz  = &dxs[sub][0][0];
        const float* pI  = dz + i0;
        const float* pJ0 = dz + j0;
        const float* pJ1 = dz + j1;
        float s3a[10], s3b[10];                        // constant-indexed -> registers
#pragma unroll
        for (int k = 0; k < 10; k++) { s3a[k] = 0.f; s3b[k] = 0.f; }
        float s2a = 0.f, s2b = 0.f, s1 = 0.f;
        for (int l = 0; l < 31; l++) {
            const float* row = dz + l * 10;
            float di  = pI[l * 10];
            float dj0 = pJ0[l * 10];
            float dj1 = pJ1[l * 10];
            float t0 = s1 + di * (1.0f / 3.0f);
            float a0 = s2a + t0 * (0.5f * dj0);
            float a1 = s2b + t0 * (0.5f * dj1);
#pragma unroll
            for (int k = 0; k < 10; k++) {
                float dk = row[k];
                s3a[k] += a0 * dk;
                s3b[k] += a1 * dk;
            }
            float u = s1 + 0.5f * di;
            s2a += u * dj0;
            s2b += u * dj1;
            s1 += di;
        }
        *(f16x2*)(sig16 + base + 10 + p0) = (f16x2){(f16)s2a, (f16)s2b};
#pragma unroll
        for (int k = 0; k < 5; k++)
            *(f16x2*)(sig16 + base + 110 + p0 * 10 + 2 * k) =
                (f16x2){(f16)s3a[2 * k], (f16)s3a[2 * k + 1]};
#pragma unroll
        for (int k = 0; k < 5; k++)
            *(f16x2*)(sig16 + base + 110 + p1 * 10 + 2 * k) =
                (f16x2){(f16)s3b[2 * k], (f16)s3b[2 * k + 1]};
    } else if (t64 < 60) {
        int c = t64 - 50;
        const float* pc = &dxs[sub][0][0] + c;
        float s = 0.f;
        for (int l = 0; l < 31; l++) s += pc[l * 10];
        sig16[base + c] = (f16)s;
    }
    if (g == 1 && t64 < 10)
        *(f16x2*)(sig16 + ((size_t)(w * 128 + b)) * 2240 + 2220 + 2 * t64) =
            (f16x2){(f16)0.0f, (f16)0.0f};
}

// ---------------------------------------------------------------- fused K2+K3
#define ACLOB \
  "a0","a1","a2","a3","a4","a5","a6","a7","a8","a9","a10","a11","a12","a13","a14","a15", \
  "a16","a17","a18","a19","a20","a21","a22","a23","a24","a25","a26","a27","a28","a29","a30","a31", \
  "a32","a33","a34","a35","a36","a37","a38","a39","a40","a41","a42","a43","a44","a45","a46","a47", \
  "a48","a49","a50","a51","a52","a53","a54","a55","a56","a57","a58","a59","a60","a61","a62","a63", \
  "a64","a65","a66","a67","a68","a69","a70","a71","a72","a73","a74","a75","a76","a77","a78","a79", \
  "a80","a81","a82","a83","a84","a85","a86","a87","a88","a89","a90","a91","a92","a93","a94","a95", \
  "a96","a97","a98","a99","a100","a101","a102","a103","a104","a105","a106","a107","a108","a109","a110","a111", \
  "a112","a113","a114","a115","a116","a117","a118","a119","a120","a121","a122","a123","a124","a125","a126","a127"

#define LF8(A0,A1, U, KT) do { \
  f32x2 _t = *(const f32x2*)(whh8 + (size_t)(((U) >> 1) * 256 + wid * 32 + ((U) & 1) * 16 + l16) * 256 + (KT) * 32 + quad * 8); \
  asm volatile("v_accvgpr_write_b32 a" #A0 ", %0\n\t" \
               "v_accvgpr_write_b32 a" #A1 ", %1" \
               :: "v"(_t[0]), "v"(_t[1]) : "a" #A0, "a" #A1); } while (0)

#define LFN(A0,A1,A2,A3, TC, KT) do { \
  f32x4 _t = *(const f32x4*)(whh16 + (size_t)(512 + wid * 32 + (TC) * 16 + l16) * 256 + (KT) * 32 + quad * 8); \
  asm volatile("v_accvgpr_write_b32 a" #A0 ", %0\n\t" \
               "v_accvgpr_write_b32 a" #A1 ", %1\n\t" \
               "v_accvgpr_write_b32 a" #A2 ", %2\n\t" \
               "v_accvgpr_write_b32 a" #A3 ", %3" \
               :: "v"(_t[0]), "v"(_t[1]), "v"(_t[2]), "v"(_t[3]) \
               : "a" #A0, "a" #A1, "a" #A2, "a" #A3); } while (0)

#define FP8GZ(P, F0,F1,F2,F3) \
  "v_mfma_f32_16x16x32_fp8_fp8 %[aR0], " P ", a[" F0 "], %[zq]\n\t" \
  "v_mfma_f32_16x16x32_fp8_fp8 %[aR1], " P ", a[" F1 "], %[zq]\n\t" \
  "v_mfma_f32_16x16x32_fp8_fp8 %[aZ0], " P ", a[" F2 "], %[zq]\n\t" \
  "v_mfma_f32_16x16x32_fp8_fp8 %[aZ1], " P ", a[" F3 "], %[zq]\n\t"

#define FP8G(P, F0,F1,F2,F3) \
  "v_mfma_f32_16x16x32_fp8_fp8 %[aR0], " P ", a[" F0 "], %[aR0]\n\t" \
  "v_mfma_f32_16x16x32_fp8_fp8 %[aR1], " P ", a[" F1 "], %[aR1]\n\t" \
  "v_mfma_f32_16x16x32_fp8_fp8 %[aZ0], " P ", a[" F2 "], %[aZ0]\n\t" \
  "v_mfma_f32_16x16x32_fp8_fp8 %[aZ1], " P ", a[" F3 "], %[aZ1]\n\t"

#define F16GZ(Q, G0,G1) \
  "v_mfma_f32_16x16x32_f16 %[aN0], " Q ", a[" G0 "], %[zq]\n\t" \
  "v_mfma_f32_16x16x32_f16 %[aN1], " Q ", a[" G1 "], %[zq]\n\t"

#define F16G(Q, G0,G1) \
  "v_mfma_f32_16x16x32_f16 %[aN0], " Q ", a[" G0 "], %[aN0]\n\t" \
  "v_mfma_f32_16x16x32_f16 %[aN1], " Q ", a[" G1 "], %[aN1]\n\t"

__global__ __launch_bounds__(512, 2) void fused_kernel(const f16* __restrict__ A,     // sig 3968 x 2240
                                                       const f16* __restrict__ Bw,    // wih 768 x 2240
                                                       const float* __restrict__ bias,
                                                       const float* __restrict__ bhh,
                                                       f16* __restrict__ Cgi,
                                                       const f16* __restrict__ whh16,
                                                       const uint8_t* __restrict__ whh8,
                                                       const float* __restrict__ W_out,
                                                       const float* __restrict__ b_out,
                                                       float* __restrict__ out,
                                                       unsigned int* __restrict__ done) {
    // LDS: gemm buffers + gru buffers coexist (112K + 26.6K = 138.6K <= 160K)
    __shared__ __align__(16) f16 As[7][128 * 32];
    __shared__ __align__(16) f16 Bs[7][128 * 32];
    __shared__ __align__(16) f16 hbufF[2][16 * 280];
    __shared__ __align__(16) uint8_t hbuf8[2][16 * 272];
    const int tid = threadIdx.x, lane = tid & 63, wid = tid >> 6;
    const int quad = lane >> 4, l16 = lane & 15;

    if (blockIdx.x < 192) {
        // ======================= GEMM role =======================
        const int lin = blockIdx.x;
        const int t = (lin & 7) + 8 * (lin / 48);
        const int nb = (lin >> 3) % 6;
        if (t >= 31) return;
        const int wm = wid >> 2, wn = wid & 3;          // wave tile: 64 x 32
        const int Mbase = t * 128, Nbase = nb * 128;
        const int lr = lane >> 2, lk = lane & 3;
        const int r0 = wid * 16;
        const f16* gaA0 = A  + (size_t)(Mbase + r0 + lr) * 2240 + lk * 8;
        const f16* gbB0 = Bw + (size_t)(Nbase + r0 + lr) * 2240 + lk * 8;

#define GISSUE(KT, BUF) do { \
        int _k0 = (KT) * 32; \
        ASYNC16(gaA0 + _k0, &As[BUF][r0 * 32]); \
        ASYNC16(gbB0 + _k0, &Bs[BUF][r0 * 32]); } while (0)

#define GCOMPUTE(BUF) do { \
        f16x8 af[4], bf[2]; \
        _Pragma("unroll") \
        for (int mt = 0; mt < 4; mt++) \
            af[mt] = *(const f16x8*)&As[BUF][(wm * 64 + mt * 16 + l16) * 32 + quad * 8]; \
        _Pragma("unroll") \
        for (int nt = 0; nt < 2; nt++) \
            bf[nt] = *(const f16x8*)&Bs[BUF][(wn * 32 + nt * 16 + l16) * 32 + quad * 8]; \
        _Pragma("unroll") \
        for (int mt = 0; mt < 4; mt++) \
            _Pragma("unroll") \
            for (int nt = 0; nt < 2; nt++) \
                acc[mt][nt] = __builtin_amdgcn_mfma_f32_16x16x32_f16(af[mt], bf[nt], acc[mt][nt], 0, 0, 0); } while (0)

        f32x4 acc[4][2];
#pragma unroll
        for (int mt = 0; mt < 4; mt++)
#pragma unroll
            for (int nt = 0; nt < 2; nt++) acc[mt][nt] = (f32x4){0.f, 0.f, 0.f, 0.f};

        GISSUE(0, 0); GISSUE(1, 1); GISSUE(2, 2);
        GISSUE(3, 3); GISSUE(4, 4); GISSUE(5, 5);
        for (int kt = 0; kt < 64; kt++) {
            asm volatile("s_waitcnt vmcnt(10) lgkmcnt(0)\n\ts_barrier" ::: "memory");
            GISSUE(kt + 6, (kt + 6) % 7);
            GCOMPUTE(kt % 7);
        }
        asm volatile("s_waitcnt vmcnt(0) lgkmcnt(0)\n\ts_barrier" ::: "memory");
        GCOMPUTE(1); GCOMPUTE(2); GCOMPUTE(3);
        GCOMPUTE(4); GCOMPUTE(5); GCOMPUTE(6);   // tiles 64..69 mod 7

        const float NEG_LOG2E = -1.4426950408889634f;
        const float TWO_LOG2E =  2.8853900817779268f;
#pragma unroll
        for (int mt = 0; mt < 4; mt++) {
            const int bbv = wm * 4 + mt;
#pragma unroll
            for (int nt = 0; nt < 2; nt++) {
                int col = Nbase + wn * 32 + nt * 16 + l16;
                float bvv = bias[col] + (col < 512 ? bhh[col] : 0.0f);
                float scl = (col < 512) ? NEG_LOG2E : TWO_LOG2E;
                int gs = col >> 8, hcc = col & 255;
                int gw = hcc >> 5, gtc = (hcc >> 4) & 1, gl = hcc & 15;
                int u = gs * 2 + gtc;
                int gtid = gw * 64 + quad * 16 + gl;
                size_t off = ((size_t)((t * 8 + bbv) * 6 + u)) * 2048 + (size_t)gtid * 4;
                f16x4 st;
#pragma unroll
                for (int rr = 0; rr < 4; rr++) st[rr] = (f16)((acc[mt][nt][rr] + bvv) * scl);
                *(f16x4*)(Cgi + off) = st;
            }
        }
        // release: all threads' gi stores visible, then one count
        __threadfence();
        __syncthreads();
        if (tid == 0) atomicAdd(done, 1u);
        return;
#undef GISSUE
#undef GCOMPUTE
    }

    // ======================= GRU role =======================
    const int bb = (int)blockIdx.x - 192;
    const f16* gi = Cgi;

    for (int i = tid; i < 16 * 280; i += 512) hbufF[1][i] = (f16)0.0f;
    for (int i = tid; i < 16 * 272; i += 512) hbuf8[1][i] = 0;

    LF8(0,1, 0,0);   LF8(2,3, 0,1);   LF8(4,5, 0,2);   LF8(6,7, 0,3);
    LF8(8,9, 0,4);   LF8(10,11, 0,5); LF8(12,13, 0,6); LF8(14,15, 0,7);
    LF8(16,17, 1,0); LF8(18,19, 1,1); LF8(20,21, 1,2); LF8(22,23, 1,3);
    LF8(24,25, 1,4); LF8(26,27, 1,5); LF8(28,29, 1,6); LF8(30,31, 1,7);
    LF8(32,33, 2,0); LF8(34,35, 2,1); LF8(36,37, 2,2); LF8(38,39, 2,3);
    LF8(40,41, 2,4); LF8(42,43, 2,5); LF8(44,45, 2,6); LF8(46,47, 2,7);
    LF8(48,49, 3,0); LF8(50,51, 3,1); LF8(52,53, 3,2); LF8(54,55, 3,3);
    LF8(56,57, 3,4); LF8(58,59, 3,5); LF8(60,61, 3,6); LF8(62,63, 3,7);
    LFN(64,65,66,67,   0,0); LFN(68,69,70,71,   0,1); LFN(72,73,74,75,   0,2); LFN(76,77,78,79,   0,3);
    LFN(80,81,82,83,   0,4); LFN(84,85,86,87,   0,5); LFN(88,89,90,91,   0,6); LFN(92,93,94,95,   0,7);
    LFN(96,97,98,99,   1,0); LFN(100,101,102,103, 1,1); LFN(104,105,106,107, 1,2); LFN(108,109,110,111, 1,3);
    LFN(112,113,114,115, 1,4); LFN(116,117,118,119, 1,5); LFN(120,121,122,123, 1,6); LFN(124,125,126,127, 1,7);

    const float C2 = 2.8853900817779268f;   // 2*log2e
    float bhn[2];
#pragma unroll
    for (int tc = 0; tc < 2; tc++) bhn[tc] = C2 * bhh[512 + wid * 32 + tc * 16 + l16];
    float hm[2][4];
#pragma unroll
    for (int tc = 0; tc < 2; tc++)
#pragma unroll
        for (int rr = 0; rr < 4; rr++) hm[tc][rr] = 0.f;

    uint32_t aF0 = (uint32_t)(uintptr_t)(__attribute__((address_space(3))) const void*)
                       (&hbufF[0][l16 * 280 + quad * 8]);
    uint32_t aF1 = (uint32_t)(uintptr_t)(__attribute__((address_space(3))) const void*)
                       (&hbufF[1][l16 * 280 + quad * 8]);
    uint32_t a80 = (uint32_t)(uintptr_t)(__attribute__((address_space(3))) const void*)
                       (&hbuf8[0][l16 * 272 + quad * 8]);
    uint32_t a81 = (uint32_t)(uintptr_t)(__attribute__((address_space(3))) const void*)
                       (&hbuf8[1][l16 * 272 + quad * 8]);

    // acquire: wait for all 186 gemm blocks, then invalidate stale cache lines
    if (tid == 0) {
        while (atomicAdd(done, 0u) < 186u) __builtin_amdgcn_s_sleep(8);
    }
    __syncthreads();
    __threadfence();

    // coalesced gi: per (t,bb) slab = 12288 f16; chunk u at u*2048; thread at tid*4
    const size_t lanebase = (size_t)bb * 12288 + (size_t)tid * 4;
    f16x4 gcur[6];
#pragma unroll
    for (int u = 0; u < 6; u++)
        gcur[u] = *(const f16x4*)(gi + lanebase + u * 2048);

    const f32x4 zq = (f32x4){0.f, 0.f, 0.f, 0.f};

    BAR_LDS();

    for (int t = 0; t < 31; t++) {
        const uint32_t a8 = (t & 1) ? a80 : a81;
        const uint32_t aF = (t & 1) ? aF0 : aF1;
        f32x4 aR0, aR1, aZ0, aZ1, aN0, aN1;
        f32x2 p0, p1, p2;
        f32x4 q0, q1, q2;
        asm volatile(
            "s_setprio 1\n\t"
            "ds_read_b64  %[p0], %[a8] offset:0\n\t"
            "ds_read_b128 %[q0], %[aF] offset:0\n\t"
            "ds_read_b64  %[p1], %[a8] offset:32\n\t"
            "ds_read_b128 %[q1], %[aF] offset:64\n\t"
            "ds_read_b64  %[p2], %[a8] offset:64\n\t"
            "ds_read_b128 %[q2], %[aF] offset:128\n\t"
            "s_waitcnt lgkmcnt(5)\n\t"
            FP8GZ("%[p0]", "0:1","16:17","32:33","48:49")
            "ds_read_b64  %[p0], %[a8] offset:96\n\t"
            "s_waitcnt lgkmcnt(5)\n\t"
            F16GZ("%[q0]", "64:67","96:99")
            "ds_read_b128 %[q0], %[aF] offset:192\n\t"
            "s_waitcnt lgkmcnt(5)\n\t"
            FP8G("%[p1]", "2:3","18:19","34:35","50:51")
            "ds_read_b64  %[p1], %[a8] offset:128\n\t"
            "s_waitcnt lgkmcnt(5)\n\t"
            F16G("%[q1]", "68:71","100:103")
            "ds_read_b128 %[q1], %[aF] offset:256\n\t"
            "s_waitcnt lgkmcnt(5)\n\t"
            FP8G("%[p2]", "4:5","20:21","36:37","52:53")
            "ds_read_b64  %[p2], %[a8] offset:160\n\t"
            "s_waitcnt lgkmcnt(5)\n\t"
            F16G("%[q2]", "72:75","104:107")
            "ds_read_b128 %[q2], %[aF] offset:320\n\t"
            "s_waitcnt lgkmcnt(5)\n\t"
            FP8G("%[p0]", "6:7","22:23","38:39","54:55")
            "ds_read_b64  %[p0], %[a8] offset:192\n\t"
            "s_waitcnt lgkmcnt(5)\n\t"
            F16G("%[q0]", "76:79","108:111")
            "ds_read_b128 %[q0], %[aF] offset:384\n\t"
            "s_waitcnt lgkmcnt(5)\n\t"
            FP8G("%[p1]", "8:9","24:25","40:41","56:57")
            "ds_read_b64  %[p1], %[a8] offset:224\n\t"
            "s_waitcnt lgkmcnt(5)\n\t"
            F16G("%[q1]", "80:83","112:115")
            "ds_read_b128 %[q1], %[aF] offset:448\n\t"
            "s_waitcnt lgkmcnt(5)\n\t"
            FP8G("%[p2]", "10:11","26:27","42:43","58:59")
            "s_waitcnt lgkmcnt(4)\n\t"
            F16G("%[q2]", "84:87","116:119")
            "s_waitcnt lgkmcnt(3)\n\t"
            FP8G("%[p0]", "12:13","28:29","44:45","60:61")
            "s_waitcnt lgkmcnt(2)\n\t"
            F16G("%[q0]", "88:91","120:123")
            "s_waitcnt lgkmcnt(1)\n\t"
            FP8G("%[p1]", "14:15","30:31","46:47","62:63")
            "s_waitcnt lgkmcnt(0)\n\t"
            F16G("%[q1]", "92:95","124:127")
            "s_setprio 0\n\t"
            "s_nop 7\n\ts_nop 7"
            : [aR0]"=&v"(aR0), [aR1]"=&v"(aR1), [aZ0]"=&v"(aZ0), [aZ1]"=&v"(aZ1),
              [aN0]"=&v"(aN0), [aN1]"=&v"(aN1),
              [p0]"=&v"(p0), [p1]"=&v"(p1), [p2]"=&v"(p2),
              [q0]"=&v"(q0), [q1]"=&v"(q1), [q2]"=&v"(q2)
            : [a8]"v"(a8), [aF]"v"(aF), [zq]"v"(zq)
            : ACLOB);

        f16* hdF = hbufF[t & 1];
        uint8_t* hd8 = hbuf8[t & 1];
        const float C1N16 = -0.09016844005556021f;   // -log2e/16
#pragma unroll
        for (int tc = 0; tc < 2; tc++) {
            const int hcx = wid * 32 + tc * 16 + l16;
            const f32x4 vR = tc ? aR1 : aR0;
            const f32x4 vZ = tc ? aZ1 : aZ0;
            const f32x4 vN = tc ? aN1 : aN0;
#pragma unroll
            for (int rr = 0; rr < 4; rr++) {
                float rg = frcp(1.f + fexp2(fmaf(C1N16, vR[rr], (float)gcur[tc][rr])));
                float zg = frcp(1.f + fexp2(fmaf(C1N16, vZ[rr], (float)gcur[2 + tc][rr])));
                float t2 = fmaf(rg, fmaf(C2, vN[rr], bhn[tc]), (float)gcur[4 + tc][rr]);
                float e2 = fexp2(t2);
                float ng = fmaf(-2.f, frcp(e2 + 1.f), 1.f);   // tanh
                float h  = fmaf(zg, hm[tc][rr] - ng, ng);     // (1-z)n + z*h
                hm[tc][rr] = h;
                hdF[(quad * 4 + rr) * 280 + hcx] = (f16)h;
                int pk = __builtin_amdgcn_cvt_pk_fp8_f32(h, h, 0, false);
                hd8[(quad * 4 + rr) * 272 + hcx] = (uint8_t)pk;
            }
        }
        {
            int tn = (t < 30) ? t + 1 : 30;
            const f16* gsrc = gi + (size_t)tn * 98304 + lanebase;
#pragma unroll
            for (int u = 0; u < 6; u++)
                gcur[u] = *(const f16x4*)(gsrc + u * 2048);
        }
        BAR_LDS();
    }
    // output head: final h in hbufF[0]
    if (tid < 160) {
        int r = tid / 10, oc = tid - r * 10;
        const f16* hfin = hbufF[0];
        float s = b_out[oc];
        for (int k = 0; k < 256; k++) s += (float)hfin[r * 280 + k] * W_out[oc * 256 + k];
        out[(bb * 16 + r) * 10 + oc] = frcp(1.f + __expf(-s));
    }
}

// ---------------------------------------------------------------- launch
extern "C" void kernel_launch(void* const* d_in, const int* in_sizes, int n_in,
                              void* d_out, int out_size, void* d_ws, size_t ws_size,
                              hipStream_t stream) {
    const float* x     = (const float*)d_in[0];
    const float* W_aug = (const float*)d_in[1];
    // d_in[2] = b_aug — cancels in dx, unused
    const float* W_ih  = (const float*)d_in[3];
    const float* W_hh  = (const float*)d_in[4];
    const float* b_ih  = (const float*)d_in[5];
    const float* b_hh  = (const float*)d_in[6];
    const float* W_out = (const float*)d_in[7];
    const float* b_out = (const float*)d_in[8];
    float* out = (float*)d_out;

    char* ws = (char*)d_ws;
    const size_t SIG_BYTES  = (size_t)3968 * 2240 * 2;           // 17,776,640
    const size_t WIH_BYTES  = (size_t)768 * 2240 * 2;            //  3,440,640
    const size_t WHH_BYTES  = (size_t)768 * 256 * 2;             //    393,216
    const size_t WHH8_BYTES = (size_t)512 * 256;                 //    131,072
    const size_t GI_BYTES   = (size_t)31 * 8 * 6 * 512 * 4 * 2;  //  6,094,848
    const size_t DONE_BYTES = 64;
    if (ws_size < SIG_BYTES + WIH_BYTES + WHH_BYTES + WHH8_BYTES + GI_BYTES + DONE_BYTES) return;
    f16* sig16    = (f16*)ws;
    f16* wih16    = (f16*)(ws + SIG_BYTES);
    f16* whh16    = (f16*)(ws + SIG_BYTES + WIH_BYTES);
    uint8_t* whh8 = (uint8_t*)(ws + SIG_BYTES + WIH_BYTES + WHH_BYTES);
    f16* giw      = (f16*)(ws + SIG_BYTES + WIH_BYTES + WHH_BYTES + WHH8_BYTES);
    unsigned int* done = (unsigned int*)(ws + SIG_BYTES + WIH_BYTES + WHH_BYTES + WHH8_BYTES + GI_BYTES);

    hipLaunchKernelGGL(prep_kernel, dim3(2920), dim3(256), 0, stream,
                       x, W_aug, W_ih, W_hh, sig16, wih16, whh16, whh8, done);
    hipLaunchKernelGGL(fused_kernel, dim3(200), dim3(512), 0, stream,
                       sig16, wih16, b_ih, b_hh, giw, whh16, whh8, W_out, b_out, out, done);
}

// Round 6
// 200.751 us; speedup vs baseline: 1.0965x; 1.0965x over previous
//
#include <hip/hip_runtime.h>
#include <hip/hip_bf16.h>
#include <stdint.h>

// Problem constants
// B=128 STREAM=512 IN_CH=4 EXTRA=5 GROUPS=2 DEPTH=3 STEP=16 LENGTH=32 RNN=256 OUT=10
// C=10 SIG_C=1110 W=31 F=2220, padded K = 2240, GEMM M = 31*128 = 3968, N = 768
// gi layout (f16, COALESCED): chunk u of thread gtid at step (t,bb):
//   f16 offset = ((t*8+bb)*6 + u)*2048 + gtid*4,  u = gs*2+gtc in [0,6)
// gi VALUES pre-scaled for exp2-based gate math:
//   r,z chunks: -log2e*(gemm + b_ih + b_hh);  n chunks: 2*log2e*(gemm + b_ih)
// GEMM: 512 threads, 128x128 tile, 7-LDS-buffer 6-deep global_load_lds pipeline.
//   LDS BANK-CONFLICT FIX (round 5 diagnosis: 8-way conflict on ds_read_b128,
//   ~50us of the ~60us gemm phase): both-sides swizzle, LDS stays linear:
//     stored(r, s) = (r ^ ((r>>2)&1),  s ^ (r&3))   [r=row in 16-row group, s=16B slot]
//   writer pre-permutes per-lane GLOBAL source; reader permutes (l16,quad).
//   Consecutive 8 lanes then hit 8 distinct 4-bank groups -> 2-way max (free).
// GRU: W_hh pinned in AGPRs a[0:127] (fp8 rz + f16 n); accumulators in VGPRs.

typedef _Float16 f16;
typedef f16  f16x2 __attribute__((ext_vector_type(2)));
typedef f16  f16x4 __attribute__((ext_vector_type(4)));
typedef f16  f16x8 __attribute__((ext_vector_type(8)));
typedef float f32x2 __attribute__((ext_vector_type(2)));
typedef float f32x4 __attribute__((ext_vector_type(4)));

#define ASYNC16(gp, lp) __builtin_amdgcn_global_load_lds( \
    (const __attribute__((address_space(1))) void*)(gp),  \
    (__attribute__((address_space(3))) void*)(lp), 16, 0, 0)

#define BAR_LDS() do { asm volatile("s_waitcnt lgkmcnt(0)" ::: "memory"); \
                       __builtin_amdgcn_s_barrier();                      \
                       asm volatile("" ::: "memory"); } while (0)

__device__ __forceinline__ float fexp2(float x) {
    float r; asm("v_exp_f32 %0, %1" : "=v"(r) : "v"(x)); return r;
}
__device__ __forceinline__ float frcp(float x) {
    float r; asm("v_rcp_f32 %0, %1" : "=v"(r) : "v"(x)); return r;
}

// ---------------------------------------------------------------- K0: prep
// blocks [0,840):    W_ih f32 -> f16 (pad 2220->2240), 8 elems/thread
// blocks [840,936):  W_hh f32 -> f16 (all) + fp8*16 (r,z rows), 8 elems/thread
// blocks [936,2920): signature chains, 4 per block (register-resident inner loop)
__global__ __launch_bounds__(256) void prep_kernel(const float* __restrict__ x,
                                                   const float* __restrict__ W_aug,
                                                   const float* __restrict__ Wih,
                                                   const float* __restrict__ Whh,
                                                   f16* __restrict__ sig16,
                                                   f16* __restrict__ wih16,
                                                   f16* __restrict__ whh16,
                                                   uint8_t* __restrict__ whh8) {
    __shared__ float dxs[4][31][10];
    const int tid = threadIdx.x;
    if (blockIdx.x < 840) {
        int c = blockIdx.x * 256 + tid;          // chunk 0..215039
        int r = c / 280, kc = (c - r * 280) * 8;
        const float* src = Wih + (size_t)r * 2220 + kc;
        f16x8 o;
        if (kc + 8 <= 2220) {
            float4 v0 = *(const float4*)(src);
            float4 v1 = *(const float4*)(src + 4);
            o[0]=(f16)v0.x; o[1]=(f16)v0.y; o[2]=(f16)v0.z; o[3]=(f16)v0.w;
            o[4]=(f16)v1.x; o[5]=(f16)v1.y; o[6]=(f16)v1.z; o[7]=(f16)v1.w;
        } else {
#pragma unroll
            for (int j = 0; j < 8; j++)
                o[j] = (f16)((kc + j < 2220) ? src[j] : 0.0f);
        }
        *(f16x8*)(wih16 + (size_t)r * 2240 + kc) = o;
        return;
    }
    if (blockIdx.x < 936) {
        int c2 = ((int)blockIdx.x - 840) * 256 + tid;    // 0..24575
        int j8 = c2 * 8;
        float w[8];
        {
            float4 v0 = *(const float4*)(Whh + j8);
            float4 v1 = *(const float4*)(Whh + j8 + 4);
            w[0]=v0.x; w[1]=v0.y; w[2]=v0.z; w[3]=v0.w;
            w[4]=v1.x; w[5]=v1.y; w[6]=v1.z; w[7]=v1.w;
        }
        f16x8 o;
#pragma unroll
        for (int j = 0; j < 8; j++) o[j] = (f16)w[j];
        *(f16x8*)(whh16 + j8) = o;
        if (j8 < 131072) {                       // r,z gate rows -> fp8 e4m3 (x16)
            uint32_t p01 = (uint32_t)__builtin_amdgcn_cvt_pk_fp8_f32(w[0]*16.f, w[1]*16.f, 0, false) & 0xffffu;
            uint32_t p23 = (uint32_t)__builtin_amdgcn_cvt_pk_fp8_f32(w[2]*16.f, w[3]*16.f, 0, false) & 0xffffu;
            uint32_t p45 = (uint32_t)__builtin_amdgcn_cvt_pk_fp8_f32(w[4]*16.f, w[5]*16.f, 0, false) & 0xffffu;
            uint32_t p67 = (uint32_t)__builtin_amdgcn_cvt_pk_fp8_f32(w[6]*16.f, w[7]*16.f, 0, false) & 0xffffu;
            uint2 st = make_uint2(p01 | (p23 << 16), p45 | (p67 << 16));
            *(uint2*)(whh8 + j8) = st;
        }
        return;
    }
    // ---- signature chains (block-uniform branch; __syncthreads safe)
    const int sub = tid >> 6, t64 = tid & 63;
    const int cid = ((int)blockIdx.x - 936) * 4 + sub;   // 0..7935
    const int w = cid % 31;
    const int bg = cid / 31;
    const int b = bg >> 1, g = bg & 1;
    if (t64 < 31) {
        int s = w * 16 + t64;
        const float4 x0 = *(const float4*)(x + ((size_t)b * 512 + s) * 4);
        const float4 x1 = *(const float4*)(x + ((size_t)b * 512 + s + 1) * 4);
        float d0 = x1.x - x0.x, d1 = x1.y - x0.y, d2 = x1.z - x0.z, d3 = x1.w - x0.w;
        dxs[sub][t64][0] = d0; dxs[sub][t64][1] = d1;
        dxs[sub][t64][2] = d2; dxs[sub][t64][3] = d3;
        dxs[sub][t64][4] = 1.0f / 511.0f;
#pragma unroll
        for (int e = 0; e < 5; e++) {
            const float* wa = W_aug + (g * 5 + e) * 4;
            dxs[sub][t64][5 + e] = d0 * wa[0] + d1 * wa[1] + d2 * wa[2] + d3 * wa[3];
        }
    }
    __syncthreads();
    size_t base = ((size_t)(w * 128 + b)) * 2240 + (size_t)g * 1110;
    if (t64 < 50) {
        int p0 = 2 * t64, p1 = p0 + 1;
        int i0 = p0 / 10, j0 = p0 % 10, j1 = j0 + 1;   // p0 even -> j1 <= 9
        // loop-invariant LDS pointers: dynamic column index resolved ONCE
        const float* dz  = &dxs[sub][0][0];
        const float* pI  = dz + i0;
        const float* pJ0 = dz + j0;
        const float* pJ1 = dz + j1;
        float s3a[10], s3b[10];                        // constant-indexed -> registers
#pragma unroll
        for (int k = 0; k < 10; k++) { s3a[k] = 0.f; s3b[k] = 0.f; }
        float s2a = 0.f, s2b = 0.f, s1 = 0.f;
        for (int l = 0; l < 31; l++) {
            const float* row = dz + l * 10;
            float di  = pI[l * 10];
            float dj0 = pJ0[l * 10];
            float dj1 = pJ1[l * 10];
            float t0 = s1 + di * (1.0f / 3.0f);
            float a0 = s2a + t0 * (0.5f * dj0);
            float a1 = s2b + t0 * (0.5f * dj1);
#pragma unroll
            for (int k = 0; k < 10; k++) {
                float dk = row[k];
                s3a[k] += a0 * dk;
                s3b[k] += a1 * dk;
            }
            float u = s1 + 0.5f * di;
            s2a += u * dj0;
            s2b += u * dj1;
            s1 += di;
        }
        *(f16x2*)(sig16 + base + 10 + p0) = (f16x2){(f16)s2a, (f16)s2b};
#pragma unroll
        for (int k = 0; k < 5; k++)
            *(f16x2*)(sig16 + base + 110 + p0 * 10 + 2 * k) =
                (f16x2){(f16)s3a[2 * k], (f16)s3a[2 * k + 1]};
#pragma unroll
        for (int k = 0; k < 5; k++)
            *(f16x2*)(sig16 + base + 110 + p1 * 10 + 2 * k) =
                (f16x2){(f16)s3b[2 * k], (f16)s3b[2 * k + 1]};
    } else if (t64 < 60) {
        int c = t64 - 50;
        const float* pc = &dxs[sub][0][0] + c;
        float s = 0.f;
        for (int l = 0; l < 31; l++) s += pc[l * 10];
        sig16[base + c] = (f16)s;
    }
    if (g == 1 && t64 < 10)
        *(f16x2*)(sig16 + ((size_t)(w * 128 + b)) * 2240 + 2220 + 2 * t64) =
            (f16x2){(f16)0.0f, (f16)0.0f};
}

// ---------------------------------------------------------------- K2: gi = sig @ W_ih.T + biases (f16, coalesced GRU layout)
// 8 waves, 7-buffer 6-deep async pipeline, conflict-free swizzled LDS.
__global__ __launch_bounds__(512) void gemm_kernel(const f16* __restrict__ A,     // 3968 x 2240
                                                   const f16* __restrict__ Bw,    // 768 x 2240 f16
                                                   const float* __restrict__ bias,
                                                   const float* __restrict__ bhh,
                                                   f16* __restrict__ Cgi) {
    const int lin = blockIdx.x;
    const int t = (lin & 7) + 8 * (lin / 48);
    const int nb = (lin >> 3) % 6;
    if (t >= 31) return;
    __shared__ __align__(16) f16 As[7][128 * 32];   // 56 KB
    __shared__ __align__(16) f16 Bs[7][128 * 32];   // 56 KB
    const int tid = threadIdx.x, lane = tid & 63, wid = tid >> 6;   // wid 0..7
    const int wm = wid >> 2, wn = wid & 3;          // wave tile: 64 rows x 32 cols
    const int Mbase = t * 128, Nbase = nb * 128;
    const int l16 = lane & 15, quad = lane >> 4;
    const int r0 = wid * 16;                        // wave stages 16 rows of A and B

    // ---- writer-side swizzle: stored(r,s) holds logical (r^((r>>2)&1), s^(r_log&3))
    // lane j writes LDS slot (lrow = j>>2, s = j&3) -> fetch logical row/slot:
    const int lrow = lane >> 2, sst = lane & 3;
    const int lrl  = lrow ^ ((lrow >> 2) & 1);      // logical local row
    const int lkl  = sst ^ (lrl & 3);               // logical 16B slot (8 f16)
    const f16* gaA0 = A  + (size_t)(Mbase + r0 + lrl) * 2240 + lkl * 8;
    const f16* gbB0 = Bw + (size_t)(Nbase + r0 + lrl) * 2240 + lkl * 8;

    // ---- reader-side swizzle: logical (row=..+l16, slot=quad) is stored at
    //      (row with l16 -> l16p, slot qA)
    const int l16p = l16 ^ ((l16 >> 2) & 1);
    const int qA   = quad ^ (l16 & 3);

#define GISSUE(KT, BUF) do { \
        int _k0 = (KT) * 32; \
        ASYNC16(gaA0 + _k0, &As[BUF][r0 * 32]); \
        ASYNC16(gbB0 + _k0, &Bs[BUF][r0 * 32]); } while (0)

#define GCOMPUTE(BUF) do { \
        f16x8 af[4], bf[2]; \
        _Pragma("unroll") \
        for (int mt = 0; mt < 4; mt++) \
            af[mt] = *(const f16x8*)&As[BUF][(wm * 64 + mt * 16 + l16p) * 32 + qA * 8]; \
        _Pragma("unroll") \
        for (int nt = 0; nt < 2; nt++) \
            bf[nt] = *(const f16x8*)&Bs[BUF][(wn * 32 + nt * 16 + l16p) * 32 + qA * 8]; \
        _Pragma("unroll") \
        for (int mt = 0; mt < 4; mt++) \
            _Pragma("unroll") \
            for (int nt = 0; nt < 2; nt++) \
                acc[mt][nt] = __builtin_amdgcn_mfma_f32_16x16x32_f16(af[mt], bf[nt], acc[mt][nt], 0, 0, 0); } while (0)

    f32x4 acc[4][2];
#pragma unroll
    for (int mt = 0; mt < 4; mt++)
#pragma unroll
        for (int nt = 0; nt < 2; nt++) acc[mt][nt] = (f32x4){0.f, 0.f, 0.f, 0.f};

    // prologue: 6 tiles in flight (12 loads per wave)
    GISSUE(0, 0); GISSUE(1, 1); GISSUE(2, 2);
    GISSUE(3, 3); GISSUE(4, 4); GISSUE(5, 5);
    for (int kt = 0; kt < 64; kt++) {
        // per-wave: wait only tile kt (oldest 2 of 12); 5 tiles stay in flight
        asm volatile("s_waitcnt vmcnt(10) lgkmcnt(0)\n\ts_barrier" ::: "memory");
        GISSUE(kt + 6, (kt + 6) % 7);
        GCOMPUTE(kt % 7);
    }
    // drain: tiles 64..69 all in flight; one full wait, then compute
    asm volatile("s_waitcnt vmcnt(0) lgkmcnt(0)\n\ts_barrier" ::: "memory");
    GCOMPUTE(1); GCOMPUTE(2); GCOMPUTE(3);
    GCOMPUTE(4); GCOMPUTE(5); GCOMPUTE(6);   // 64..69 mod 7

    // epilogue: coalesced chunk layout + exp2 pre-scaling
    const float NEG_LOG2E = -1.4426950408889634f;
    const float TWO_LOG2E =  2.8853900817779268f;
#pragma unroll
    for (int mt = 0; mt < 4; mt++) {
        const int bbv = wm * 4 + mt;
#pragma unroll
        for (int nt = 0; nt < 2; nt++) {
            int col = Nbase + wn * 32 + nt * 16 + l16;
            float bvv = bias[col] + (col < 512 ? bhh[col] : 0.0f);   // fold b_hh into r,z
            float scl = (col < 512) ? NEG_LOG2E : TWO_LOG2E;
            int gs = col >> 8, hcc = col & 255;
            int gw = hcc >> 5, gtc = (hcc >> 4) & 1, gl = hcc & 15;
            int u = gs * 2 + gtc;
            int gtid = gw * 64 + quad * 16 + gl;
            size_t off = ((size_t)((t * 8 + bbv) * 6 + u)) * 2048 + (size_t)gtid * 4;
            f16x4 st;
#pragma unroll
            for (int rr = 0; rr < 4; rr++) st[rr] = (f16)((acc[mt][nt][rr] + bvv) * scl);
            *(f16x4*)(Cgi + off) = st;
        }
    }
#undef GISSUE
#undef GCOMPUTE
}

// ---------------------------------------------------------------- K3: GRU scan
// W_hh fragments pinned a[0:127]; accumulators in VGPRs (unified file).
#define ACLOB \
  "a0","a1","a2","a3","a4","a5","a6","a7","a8","a9","a10","a11","a12","a13","a14","a15", \
  "a16","a17","a18","a19","a20","a21","a22","a23","a24","a25","a26","a27","a28","a29","a30","a31", \
  "a32","a33","a34","a35","a36","a37","a38","a39","a40","a41","a42","a43","a44","a45","a46","a47", \
  "a48","a49","a50","a51","a52","a53","a54","a55","a56","a57","a58","a59","a60","a61","a62","a63", \
  "a64","a65","a66","a67","a68","a69","a70","a71","a72","a73","a74","a75","a76","a77","a78","a79", \
  "a80","a81","a82","a83","a84","a85","a86","a87","a88","a89","a90","a91","a92","a93","a94","a95", \
  "a96","a97","a98","a99","a100","a101","a102","a103","a104","a105","a106","a107","a108","a109","a110","a111", \
  "a112","a113","a114","a115","a116","a117","a118","a119","a120","a121","a122","a123","a124","a125","a126","a127"

#define LF8(A0,A1, U, KT) do { \
  f32x2 _t = *(const f32x2*)(whh8 + (size_t)(((U) >> 1) * 256 + wid * 32 + ((U) & 1) * 16 + l16) * 256 + (KT) * 32 + quad * 8); \
  asm volatile("v_accvgpr_write_b32 a" #A0 ", %0\n\t" \
               "v_accvgpr_write_b32 a" #A1 ", %1" \
               :: "v"(_t[0]), "v"(_t[1]) : "a" #A0, "a" #A1); } while (0)

#define LFN(A0,A1,A2,A3, TC, KT) do { \
  f32x4 _t = *(const f32x4*)(whh16 + (size_t)(512 + wid * 32 + (TC) * 16 + l16) * 256 + (KT) * 32 + quad * 8); \
  asm volatile("v_accvgpr_write_b32 a" #A0 ", %0\n\t" \
               "v_accvgpr_write_b32 a" #A1 ", %1\n\t" \
               "v_accvgpr_write_b32 a" #A2 ", %2\n\t" \
               "v_accvgpr_write_b32 a" #A3 ", %3" \
               :: "v"(_t[0]), "v"(_t[1]), "v"(_t[2]), "v"(_t[3]) \
               : "a" #A0, "a" #A1, "a" #A2, "a" #A3); } while (0)

// fp8 gate MFMA groups: accumulators %[aR0],%[aR1],%[aZ0],%[aZ1] (VGPR quads)
#define FP8GZ(P, F0,F1,F2,F3) \
  "v_mfma_f32_16x16x32_fp8_fp8 %[aR0], " P ", a[" F0 "], %[zq]\n\t" \
  "v_mfma_f32_16x16x32_fp8_fp8 %[aR1], " P ", a[" F1 "], %[zq]\n\t" \
  "v_mfma_f32_16x16x32_fp8_fp8 %[aZ0], " P ", a[" F2 "], %[zq]\n\t" \
  "v_mfma_f32_16x16x32_fp8_fp8 %[aZ1], " P ", a[" F3 "], %[zq]\n\t"

#define FP8G(P, F0,F1,F2,F3) \
  "v_mfma_f32_16x16x32_fp8_fp8 %[aR0], " P ", a[" F0 "], %[aR0]\n\t" \
  "v_mfma_f32_16x16x32_fp8_fp8 %[aR1], " P ", a[" F1 "], %[aR1]\n\t" \
  "v_mfma_f32_16x16x32_fp8_fp8 %[aZ0], " P ", a[" F2 "], %[aZ0]\n\t" \
  "v_mfma_f32_16x16x32_fp8_fp8 %[aZ1], " P ", a[" F3 "], %[aZ1]\n\t"

#define F16GZ(Q, G0,G1) \
  "v_mfma_f32_16x16x32_f16 %[aN0], " Q ", a[" G0 "], %[zq]\n\t" \
  "v_mfma_f32_16x16x32_f16 %[aN1], " Q ", a[" G1 "], %[zq]\n\t"

#define F16G(Q, G0,G1) \
  "v_mfma_f32_16x16x32_f16 %[aN0], " Q ", a[" G0 "], %[aN0]\n\t" \
  "v_mfma_f32_16x16x32_f16 %[aN1], " Q ", a[" G1 "], %[aN1]\n\t"

__global__ __launch_bounds__(512, 2) void gru_kernel(const f16* __restrict__ gi,
                                                     const f16* __restrict__ whh16,
                                                     const uint8_t* __restrict__ whh8,
                                                     const float* __restrict__ b_hh,
                                                     const float* __restrict__ W_out,
                                                     const float* __restrict__ b_out,
                                                     float* __restrict__ out) {
    __shared__ __align__(16) f16 hbufF[2][16 * 280];      // f16 h (n-gate A + head)
    __shared__ __align__(16) uint8_t hbuf8[2][16 * 272];  // fp8 h (rz A)
    const int tid = threadIdx.x, lane = tid & 63, wid = tid >> 6;   // wid 0..7
    const int quad = lane >> 4, l16 = lane & 15;
    const int bb = blockIdx.x;

    for (int i = tid; i < 16 * 280; i += 512) hbufF[1][i] = (f16)0.0f;
    for (int i = tid; i < 16 * 272; i += 512) hbuf8[1][i] = 0;

    LF8(0,1, 0,0);   LF8(2,3, 0,1);   LF8(4,5, 0,2);   LF8(6,7, 0,3);
    LF8(8,9, 0,4);   LF8(10,11, 0,5); LF8(12,13, 0,6); LF8(14,15, 0,7);
    LF8(16,17, 1,0); LF8(18,19, 1,1); LF8(20,21, 1,2); LF8(22,23, 1,3);
    LF8(24,25, 1,4); LF8(26,27, 1,5); LF8(28,29, 1,6); LF8(30,31, 1,7);
    LF8(32,33, 2,0); LF8(34,35, 2,1); LF8(36,37, 2,2); LF8(38,39, 2,3);
    LF8(40,41, 2,4); LF8(42,43, 2,5); LF8(44,45, 2,6); LF8(46,47, 2,7);
    LF8(48,49, 3,0); LF8(50,51, 3,1); LF8(52,53, 3,2); LF8(54,55, 3,3);
    LF8(56,57, 3,4); LF8(58,59, 3,5); LF8(60,61, 3,6); LF8(62,63, 3,7);
    LFN(64,65,66,67,   0,0); LFN(68,69,70,71,   0,1); LFN(72,73,74,75,   0,2); LFN(76,77,78,79,   0,3);
    LFN(80,81,82,83,   0,4); LFN(84,85,86,87,   0,5); LFN(88,89,90,91,   0,6); LFN(92,93,94,95,   0,7);
    LFN(96,97,98,99,   1,0); LFN(100,101,102,103, 1,1); LFN(104,105,106,107, 1,2); LFN(108,109,110,111, 1,3);
    LFN(112,113,114,115, 1,4); LFN(116,117,118,119, 1,5); LFN(120,121,122,123, 1,6); LFN(124,125,126,127, 1,7);

    const float C2 = 2.8853900817779268f;   // 2*log2e
    float bhn[2];
#pragma unroll
    for (int tc = 0; tc < 2; tc++) bhn[tc] = C2 * b_hh[512 + wid * 32 + tc * 16 + l16];
    float hm[2][4];
#pragma unroll
    for (int tc = 0; tc < 2; tc++)
#pragma unroll
        for (int rr = 0; rr < 4; rr++) hm[tc][rr] = 0.f;

    uint32_t aF0 = (uint32_t)(uintptr_t)(__attribute__((address_space(3))) const void*)
                       (&hbufF[0][l16 * 280 + quad * 8]);
    uint32_t aF1 = (uint32_t)(uintptr_t)(__attribute__((address_space(3))) const void*)
                       (&hbufF[1][l16 * 280 + quad * 8]);
    uint32_t a80 = (uint32_t)(uintptr_t)(__attribute__((address_space(3))) const void*)
                       (&hbuf8[0][l16 * 272 + quad * 8]);
    uint32_t a81 = (uint32_t)(uintptr_t)(__attribute__((address_space(3))) const void*)
                       (&hbuf8[1][l16 * 272 + quad * 8]);

    // coalesced gi: per (t,bb) slab = 12288 f16; chunk u at u*2048; thread at tid*4
    const size_t lanebase = (size_t)bb * 12288 + (size_t)tid * 4;
    f16x4 gcur[6];
#pragma unroll
    for (int u = 0; u < 6; u++)
        gcur[u] = *(const f16x4*)(gi + lanebase + u * 2048);

    const f32x4 zq = (f32x4){0.f, 0.f, 0.f, 0.f};

    BAR_LDS();

    for (int t = 0; t < 31; t++) {
        const uint32_t a8 = (t & 1) ? a80 : a81;
        const uint32_t aF = (t & 1) ? aF0 : aF1;
        f32x4 aR0, aR1, aZ0, aZ1, aN0, aN1;
        f32x2 p0, p1, p2;
        f32x4 q0, q1, q2;
        asm volatile(
            "s_setprio 1\n\t"
            "ds_read_b64  %[p0], %[a8] offset:0\n\t"
            "ds_read_b128 %[q0], %[aF] offset:0\n\t"
            "ds_read_b64  %[p1], %[a8] offset:32\n\t"
            "ds_read_b128 %[q1], %[aF] offset:64\n\t"
            "ds_read_b64  %[p2], %[a8] offset:64\n\t"
            "ds_read_b128 %[q2], %[aF] offset:128\n\t"
            "s_waitcnt lgkmcnt(5)\n\t"
            FP8GZ("%[p0]", "0:1","16:17","32:33","48:49")
            "ds_read_b64  %[p0], %[a8] offset:96\n\t"
            "s_waitcnt lgkmcnt(5)\n\t"
            F16GZ("%[q0]", "64:67","96:99")
            "ds_read_b128 %[q0], %[aF] offset:192\n\t"
            "s_waitcnt lgkmcnt(5)\n\t"
            FP8G("%[p1]", "2:3","18:19","34:35","50:51")
            "ds_read_b64  %[p1], %[a8] offset:128\n\t"
            "s_waitcnt lgkmcnt(5)\n\t"
            F16G("%[q1]", "68:71","100:103")
            "ds_read_b128 %[q1], %[aF] offset:256\n\t"
            "s_waitcnt lgkmcnt(5)\n\t"
            FP8G("%[p2]", "4:5","20:21","36:37","52:53")
            "ds_read_b64  %[p2], %[a8] offset:160\n\t"
            "s_waitcnt lgkmcnt(5)\n\t"
            F16G("%[q2]", "72:75","104:107")
            "ds_read_b128 %[q2], %[aF] offset:320\n\t"
            "s_waitcnt lgkmcnt(5)\n\t"
            FP8G("%[p0]", "6:7","22:23","38:39","54:55")
            "ds_read_b64  %[p0], %[a8] offset:192\n\t"
            "s_waitcnt lgkmcnt(5)\n\t"
            F16G("%[q0]", "76:79","108:111")
            "ds_read_b128 %[q0], %[aF] offset:384\n\t"
            "s_waitcnt lgkmcnt(5)\n\t"
            FP8G("%[p1]", "8:9","24:25","40:41","56:57")
            "ds_read_b64  %[p1], %[a8] offset:224\n\t"
            "s_waitcnt lgkmcnt(5)\n\t"
            F16G("%[q1]", "80:83","112:115")
            "ds_read_b128 %[q1], %[aF] offset:448\n\t"
            "s_waitcnt lgkmcnt(5)\n\t"
            FP8G("%[p2]", "10:11","26:27","42:43","58:59")
            "s_waitcnt lgkmcnt(4)\n\t"
            F16G("%[q2]", "84:87","116:119")
            "s_waitcnt lgkmcnt(3)\n\t"
            FP8G("%[p0]", "12:13","28:29","44:45","60:61")
            "s_waitcnt lgkmcnt(2)\n\t"
            F16G("%[q0]", "88:91","120:123")
            "s_waitcnt lgkmcnt(1)\n\t"
            FP8G("%[p1]", "14:15","30:31","46:47","62:63")
            "s_waitcnt lgkmcnt(0)\n\t"
            F16G("%[q1]", "92:95","124:127")
            "s_setprio 0\n\t"
            "s_nop 7\n\ts_nop 7"
            : [aR0]"=&v"(aR0), [aR1]"=&v"(aR1), [aZ0]"=&v"(aZ0), [aZ1]"=&v"(aZ1),
              [aN0]"=&v"(aN0), [aN1]"=&v"(aN1),
              [p0]"=&v"(p0), [p1]"=&v"(p1), [p2]"=&v"(p2),
              [q0]"=&v"(q0), [q1]"=&v"(q1), [q2]"=&v"(q2)
            : [a8]"v"(a8), [aF]"v"(aF), [zq]"v"(zq)
            : ACLOB);

        // gate math (exp2 form): accR/accZ are rz matmul (x1/16), accN is n matmul
        f16* hdF = hbufF[t & 1];
        uint8_t* hd8 = hbuf8[t & 1];
        const float C1N16 = -0.09016844005556021f;   // -log2e/16
#pragma unroll
        for (int tc = 0; tc < 2; tc++) {
            const int hcx = wid * 32 + tc * 16 + l16;
            const f32x4 vR = tc ? aR1 : aR0;
            const f32x4 vZ = tc ? aZ1 : aZ0;
            const f32x4 vN = tc ? aN1 : aN0;
#pragma unroll
            for (int rr = 0; rr < 4; rr++) {
                float rg = frcp(1.f + fexp2(fmaf(C1N16, vR[rr], (float)gcur[tc][rr])));
                float zg = frcp(1.f + fexp2(fmaf(C1N16, vZ[rr], (float)gcur[2 + tc][rr])));
                float t2 = fmaf(rg, fmaf(C2, vN[rr], bhn[tc]), (float)gcur[4 + tc][rr]);
                float e2 = fexp2(t2);
                float ng = fmaf(-2.f, frcp(e2 + 1.f), 1.f);   // tanh
                float h  = fmaf(zg, hm[tc][rr] - ng, ng);     // (1-z)n + z*h
                hm[tc][rr] = h;
                hdF[(quad * 4 + rr) * 280 + hcx] = (f16)h;
                int pk = __builtin_amdgcn_cvt_pk_fp8_f32(h, h, 0, false);
                hd8[(quad * 4 + rr) * 272 + hcx] = (uint8_t)pk;
            }
        }
        // prefetch gi for t+1 (registers; survives lgkm-only barrier)
        {
            int tn = (t < 30) ? t + 1 : 30;
            const f16* gsrc = gi + (size_t)tn * 98304 + lanebase;
#pragma unroll
            for (int u = 0; u < 6; u++)
                gcur[u] = *(const f16x4*)(gsrc + u * 2048);
        }
        BAR_LDS();
    }
    // output head: final h in hbufF[0]
    if (tid < 160) {
        int r = tid / 10, oc = tid - r * 10;
        const f16* hfin = hbufF[0];
        float s = b_out[oc];
        for (int k = 0; k < 256; k++) s += (float)hfin[r * 280 + k] * W_out[oc * 256 + k];
        out[(bb * 16 + r) * 10 + oc] = frcp(1.f + __expf(-s));
    }
}

// ---------------------------------------------------------------- launch
extern "C" void kernel_launch(void* const* d_in, const int* in_sizes, int n_in,
                              void* d_out, int out_size, void* d_ws, size_t ws_size,
                              hipStream_t stream) {
    const float* x     = (const float*)d_in[0];
    const float* W_aug = (const float*)d_in[1];
    // d_in[2] = b_aug — cancels in dx, unused
    const float* W_ih  = (const float*)d_in[3];
    const float* W_hh  = (const float*)d_in[4];
    const float* b_ih  = (const float*)d_in[5];
    const float* b_hh  = (const float*)d_in[6];
    const float* W_out = (const float*)d_in[7];
    const float* b_out = (const float*)d_in[8];
    float* out = (float*)d_out;

    char* ws = (char*)d_ws;
    const size_t SIG_BYTES  = (size_t)3968 * 2240 * 2;           // 17,776,640
    const size_t WIH_BYTES  = (size_t)768 * 2240 * 2;            //  3,440,640
    const size_t WHH_BYTES  = (size_t)768 * 256 * 2;             //    393,216
    const size_t WHH8_BYTES = (size_t)512 * 256;                 //    131,072
    const size_t GI_BYTES   = (size_t)31 * 8 * 6 * 512 * 4 * 2;  //  6,094,848
    if (ws_size < SIG_BYTES + WIH_BYTES + WHH_BYTES + WHH8_BYTES + GI_BYTES) return;
    f16* sig16    = (f16*)ws;
    f16* wih16    = (f16*)(ws + SIG_BYTES);
    f16* whh16    = (f16*)(ws + SIG_BYTES + WIH_BYTES);
    uint8_t* whh8 = (uint8_t*)(ws + SIG_BYTES + WIH_BYTES + WHH_BYTES);
    f16* giw      = (f16*)(ws + SIG_BYTES + WIH_BYTES + WHH_BYTES + WHH8_BYTES);

    hipLaunchKernelGGL(prep_kernel, dim3(2920), dim3(256), 0, stream,
                       x, W_aug, W_ih, W_hh, sig16, wih16, whh16, whh8);
    hipLaunchKernelGGL(gemm_kernel, dim3(192), dim3(512), 0, stream,
                       sig16, wih16, b_ih, b_hh, giw);
    hipLaunchKernelGGL(gru_kernel, dim3(8), dim3(512), 0, stream,
                       giw, whh16, whh8, b_hh, W_out, b_out, out);
}

// Round 7
// 200.128 us; speedup vs baseline: 1.0999x; 1.0031x over previous
//
#include <hip/hip_runtime.h>
#include <hip/hip_bf16.h>
#include <stdint.h>

// Problem constants
// B=128 STREAM=512 IN_CH=4 EXTRA=5 GROUPS=2 DEPTH=3 STEP=16 LENGTH=32 RNN=256 OUT=10
// C=10 SIG_C=1110 W=31 F=2220, padded K = 2240, GEMM M = 31*128 = 3968, N = 768
// gi layout (f16, COALESCED): chunk u of thread gtid at step (t,bb):
//   f16 offset = ((t*8+bb)*6 + u)*2048 + gtid*4,  u = gs*2+gtc in [0,6)
// gi VALUES pre-scaled for exp2-based gate math:
//   r,z chunks: -log2e*(gemm + b_ih + b_hh);  n chunks: 2*log2e*(gemm + b_ih)
// GEMM (round 7): 64x128 tiles -> 372 blocks -> 2 blocks/CU so barrier bubbles
//   of one block overlap compute of the other (round-6 lesson: conflicts were
//   costless; the 1475cy/K-tile came from single-block lockstep). 256 thr,
//   4 waves, 6-LDS-buffer 5-deep global_load_lds pipeline, vmcnt(12) steady.
// prep (round 7): signature rows staged in LDS, then coalesced f16x2 copy-out
//   (old s3 stores were 40B-strided scatter => ~10x write amplification).
// GRU: unchanged (W_hh pinned in AGPRs, VGPR accumulators, exp2 gate math).

typedef _Float16 f16;
typedef f16  f16x2 __attribute__((ext_vector_type(2)));
typedef f16  f16x4 __attribute__((ext_vector_type(4)));
typedef f16  f16x8 __attribute__((ext_vector_type(8)));
typedef float f32x2 __attribute__((ext_vector_type(2)));
typedef float f32x4 __attribute__((ext_vector_type(4)));

#define ASYNC16(gp, lp) __builtin_amdgcn_global_load_lds( \
    (const __attribute__((address_space(1))) void*)(gp),  \
    (__attribute__((address_space(3))) void*)(lp), 16, 0, 0)

#define BAR_LDS() do { asm volatile("s_waitcnt lgkmcnt(0)" ::: "memory"); \
                       __builtin_amdgcn_s_barrier();                      \
                       asm volatile("" ::: "memory"); } while (0)

__device__ __forceinline__ float fexp2(float x) {
    float r; asm("v_exp_f32 %0, %1" : "=v"(r) : "v"(x)); return r;
}
__device__ __forceinline__ float frcp(float x) {
    float r; asm("v_rcp_f32 %0, %1" : "=v"(r) : "v"(x)); return r;
}

// ---------------------------------------------------------------- K0: prep
// blocks [0,840):    W_ih f32 -> f16 (pad 2220->2240), 8 elems/thread
// blocks [840,936):  W_hh f32 -> f16 (all) + fp8*16 (r,z rows), 8 elems/thread
// blocks [936,2920): signature chains, 4/block; LDS-staged coalesced row store
__global__ __launch_bounds__(256) void prep_kernel(const float* __restrict__ x,
                                                   const float* __restrict__ W_aug,
                                                   const float* __restrict__ Wih,
                                                   const float* __restrict__ Whh,
                                                   f16* __restrict__ sig16,
                                                   f16* __restrict__ wih16,
                                                   f16* __restrict__ whh16,
                                                   uint8_t* __restrict__ whh8) {
    __shared__ float dxs[4][31][10];
    __shared__ f16 srow[4][1112];                  // per-chain staging (1110 + pad)
    const int tid = threadIdx.x;
    if (blockIdx.x < 840) {
        int c = blockIdx.x * 256 + tid;          // chunk 0..215039
        int r = c / 280, kc = (c - r * 280) * 8;
        const float* src = Wih + (size_t)r * 2220 + kc;
        f16x8 o;
        if (kc + 8 <= 2220) {
            float4 v0 = *(const float4*)(src);
            float4 v1 = *(const float4*)(src + 4);
            o[0]=(f16)v0.x; o[1]=(f16)v0.y; o[2]=(f16)v0.z; o[3]=(f16)v0.w;
            o[4]=(f16)v1.x; o[5]=(f16)v1.y; o[6]=(f16)v1.z; o[7]=(f16)v1.w;
        } else {
#pragma unroll
            for (int j = 0; j < 8; j++)
                o[j] = (f16)((kc + j < 2220) ? src[j] : 0.0f);
        }
        *(f16x8*)(wih16 + (size_t)r * 2240 + kc) = o;
        return;
    }
    if (blockIdx.x < 936) {
        int c2 = ((int)blockIdx.x - 840) * 256 + tid;    // 0..24575
        int j8 = c2 * 8;
        float w[8];
        {
            float4 v0 = *(const float4*)(Whh + j8);
            float4 v1 = *(const float4*)(Whh + j8 + 4);
            w[0]=v0.x; w[1]=v0.y; w[2]=v0.z; w[3]=v0.w;
            w[4]=v1.x; w[5]=v1.y; w[6]=v1.z; w[7]=v1.w;
        }
        f16x8 o;
#pragma unroll
        for (int j = 0; j < 8; j++) o[j] = (f16)w[j];
        *(f16x8*)(whh16 + j8) = o;
        if (j8 < 131072) {                       // r,z gate rows -> fp8 e4m3 (x16)
            uint32_t p01 = (uint32_t)__builtin_amdgcn_cvt_pk_fp8_f32(w[0]*16.f, w[1]*16.f, 0, false) & 0xffffu;
            uint32_t p23 = (uint32_t)__builtin_amdgcn_cvt_pk_fp8_f32(w[2]*16.f, w[3]*16.f, 0, false) & 0xffffu;
            uint32_t p45 = (uint32_t)__builtin_amdgcn_cvt_pk_fp8_f32(w[4]*16.f, w[5]*16.f, 0, false) & 0xffffu;
            uint32_t p67 = (uint32_t)__builtin_amdgcn_cvt_pk_fp8_f32(w[6]*16.f, w[7]*16.f, 0, false) & 0xffffu;
            uint2 st = make_uint2(p01 | (p23 << 16), p45 | (p67 << 16));
            *(uint2*)(whh8 + j8) = st;
        }
        return;
    }
    // ---- signature chains (block-uniform branch; __syncthreads safe)
    const int sub = tid >> 6, t64 = tid & 63;
    const int cid = ((int)blockIdx.x - 936) * 4 + sub;   // 0..7935
    const int w = cid % 31;
    const int bg = cid / 31;
    const int b = bg >> 1, g = bg & 1;
    if (t64 < 31) {
        int s = w * 16 + t64;
        const float4 x0 = *(const float4*)(x + ((size_t)b * 512 + s) * 4);
        const float4 x1 = *(const float4*)(x + ((size_t)b * 512 + s + 1) * 4);
        float d0 = x1.x - x0.x, d1 = x1.y - x0.y, d2 = x1.z - x0.z, d3 = x1.w - x0.w;
        dxs[sub][t64][0] = d0; dxs[sub][t64][1] = d1;
        dxs[sub][t64][2] = d2; dxs[sub][t64][3] = d3;
        dxs[sub][t64][4] = 1.0f / 511.0f;
#pragma unroll
        for (int e = 0; e < 5; e++) {
            const float* wa = W_aug + (g * 5 + e) * 4;
            dxs[sub][t64][5 + e] = d0 * wa[0] + d1 * wa[1] + d2 * wa[2] + d3 * wa[3];
        }
    }
    __syncthreads();
    size_t base = ((size_t)(w * 128 + b)) * 2240 + (size_t)g * 1110;
    if (t64 < 50) {
        int p0 = 2 * t64, p1 = p0 + 1;
        int i0 = p0 / 10, j0 = p0 % 10, j1 = j0 + 1;   // p0 even -> j1 <= 9
        // loop-invariant LDS pointers: dynamic column index resolved ONCE
        const float* dz  = &dxs[sub][0][0];
        const float* pI  = dz + i0;
        const float* pJ0 = dz + j0;
        const float* pJ1 = dz + j1;
        float s3a[10], s3b[10];                        // constant-indexed -> registers
#pragma unroll
        for (int k = 0; k < 10; k++) { s3a[k] = 0.f; s3b[k] = 0.f; }
        float s2a = 0.f, s2b = 0.f, s1 = 0.f;
        for (int l = 0; l < 31; l++) {
            const float* row = dz + l * 10;
            float di  = pI[l * 10];
            float dj0 = pJ0[l * 10];
            float dj1 = pJ1[l * 10];
            float t0 = s1 + di * (1.0f / 3.0f);
            float a0 = s2a + t0 * (0.5f * dj0);
            float a1 = s2b + t0 * (0.5f * dj1);
#pragma unroll
            for (int k = 0; k < 10; k++) {
                float dk = row[k];
                s3a[k] += a0 * dk;
                s3b[k] += a1 * dk;
            }
            float u = s1 + 0.5f * di;
            s2a += u * dj0;
            s2b += u * dj1;
            s1 += di;
        }
        // stage into LDS (scatter is free there); global store happens coalesced below
        *(f16x2*)&srow[sub][10 + p0] = (f16x2){(f16)s2a, (f16)s2b};
#pragma unroll
        for (int k = 0; k < 5; k++)
            *(f16x2*)&srow[sub][110 + p0 * 10 + 2 * k] =
                (f16x2){(f16)s3a[2 * k], (f16)s3a[2 * k + 1]};
#pragma unroll
        for (int k = 0; k < 5; k++)
            *(f16x2*)&srow[sub][110 + p1 * 10 + 2 * k] =
                (f16x2){(f16)s3b[2 * k], (f16)s3b[2 * k + 1]};
    } else if (t64 < 60) {
        int c = t64 - 50;
        const float* pc = &dxs[sub][0][0] + c;
        float s = 0.f;
        for (int l = 0; l < 31; l++) s += pc[l * 10];
        srow[sub][c] = (f16)s;
    }
    __syncthreads();
    // coalesced copy-out: lane j writes 4B at base*2 + 4j (contiguous across lanes)
    for (int j = t64; j < 555; j += 64)
        *(f16x2*)(sig16 + base + 2 * j) = *(const f16x2*)&srow[sub][2 * j];
    if (g == 1 && t64 < 10)
        *(f16x2*)(sig16 + ((size_t)(w * 128 + b)) * 2240 + 2220 + 2 * t64) =
            (f16x2){(f16)0.0f, (f16)0.0f};
}

// ---------------------------------------------------------------- K2: gi = sig @ W_ih.T + biases (f16, coalesced GRU layout)
// 64x128 tile, 372 blocks (2/CU), 4 waves, 6-buffer 5-deep async pipeline.
__global__ __launch_bounds__(256) void gemm_kernel(const f16* __restrict__ A,     // 3968 x 2240
                                                   const f16* __restrict__ Bw,    // 768 x 2240 f16
                                                   const float* __restrict__ bias,
                                                   const float* __restrict__ bhh,
                                                   f16* __restrict__ Cgi) {
    const int lin = blockIdx.x;          // 372 = 62 mb x 6 nb
    const int nb = lin % 6;
    const int mb = lin / 6;              // 0..61
    const int t = mb >> 1, half = mb & 1;
    __shared__ __align__(16) f16 As[6][64 * 32];    // 24 KB
    __shared__ __align__(16) f16 Bs[6][128 * 32];   // 48 KB  (total 72 KB -> 2 blocks/CU)
    const int tid = threadIdx.x, lane = tid & 63, wid = tid >> 6;   // wid 0..3
    const int l16 = lane & 15, quad = lane >> 4;
    const int lrow = lane >> 2, lk = lane & 3;
    const int Nbase = nb * 128;
    // per-wave staging: A rows [wid*16,+16), B rows [wid*32,+32)
    const f16* gaA  = A  + (size_t)(t * 128 + half * 64 + wid * 16 + lrow) * 2240 + lk * 8;
    const f16* gbB0 = Bw + (size_t)(Nbase + wid * 32 + lrow) * 2240 + lk * 8;
    const f16* gbB1 = Bw + (size_t)(Nbase + wid * 32 + 16 + lrow) * 2240 + lk * 8;

#define GISSUE(KT, BUF) do { \
        int _k0 = (KT) * 32; \
        ASYNC16(gaA  + _k0, &As[BUF][(wid * 16) * 32]); \
        ASYNC16(gbB0 + _k0, &Bs[BUF][(wid * 32) * 32]); \
        ASYNC16(gbB1 + _k0, &Bs[BUF][(wid * 32 + 16) * 32]); } while (0)

#define GCOMPUTE(BUF) do { \
        f16x8 af[4], bf[2]; \
        _Pragma("unroll") \
        for (int mt = 0; mt < 4; mt++) \
            af[mt] = *(const f16x8*)&As[BUF][(mt * 16 + l16) * 32 + quad * 8]; \
        _Pragma("unroll") \
        for (int nt = 0; nt < 2; nt++) \
            bf[nt] = *(const f16x8*)&Bs[BUF][(wid * 32 + nt * 16 + l16) * 32 + quad * 8]; \
        _Pragma("unroll") \
        for (int mt = 0; mt < 4; mt++) \
            _Pragma("unroll") \
            for (int nt = 0; nt < 2; nt++) \
                acc[mt][nt] = __builtin_amdgcn_mfma_f32_16x16x32_f16(af[mt], bf[nt], acc[mt][nt], 0, 0, 0); } while (0)

    f32x4 acc[4][2];
#pragma unroll
    for (int mt = 0; mt < 4; mt++)
#pragma unroll
        for (int nt = 0; nt < 2; nt++) acc[mt][nt] = (f32x4){0.f, 0.f, 0.f, 0.f};

    // prologue: 5 tiles in flight (15 loads per wave)
    GISSUE(0, 0); GISSUE(1, 1); GISSUE(2, 2); GISSUE(3, 3); GISSUE(4, 4);
    for (int kt = 0; kt < 65; kt++) {
        // per-wave: wait only tile kt (oldest 3 of 15); 4 tiles stay in flight
        asm volatile("s_waitcnt vmcnt(12) lgkmcnt(0)\n\ts_barrier" ::: "memory");
        GISSUE(kt + 5, (kt + 5) % 6);
        GCOMPUTE(kt % 6);
    }
    // drain: tiles 65..69 all in flight; one full wait, then compute
    asm volatile("s_waitcnt vmcnt(0) lgkmcnt(0)\n\ts_barrier" ::: "memory");
    GCOMPUTE(5); GCOMPUTE(0); GCOMPUTE(1); GCOMPUTE(2); GCOMPUTE(3);   // 65..69 mod 6

    // epilogue: coalesced chunk layout + exp2 pre-scaling
    const float NEG_LOG2E = -1.4426950408889634f;
    const float TWO_LOG2E =  2.8853900817779268f;
#pragma unroll
    for (int mt = 0; mt < 4; mt++) {
        const int bbv = half * 4 + mt;
#pragma unroll
        for (int nt = 0; nt < 2; nt++) {
            int col = Nbase + wid * 32 + nt * 16 + l16;
            float bvv = bias[col] + (col < 512 ? bhh[col] : 0.0f);   // fold b_hh into r,z
            float scl = (col < 512) ? NEG_LOG2E : TWO_LOG2E;
            int gs = col >> 8, hcc = col & 255;
            int gw = hcc >> 5, gtc = (hcc >> 4) & 1, gl = hcc & 15;
            int u = gs * 2 + gtc;
            int gtid = gw * 64 + quad * 16 + gl;
            size_t off = ((size_t)((t * 8 + bbv) * 6 + u)) * 2048 + (size_t)gtid * 4;
            f16x4 st;
#pragma unroll
            for (int rr = 0; rr < 4; rr++) st[rr] = (f16)((acc[mt][nt][rr] + bvv) * scl);
            *(f16x4*)(Cgi + off) = st;
        }
    }
#undef GISSUE
#undef GCOMPUTE
}

// ---------------------------------------------------------------- K3: GRU scan
// W_hh fragments pinned a[0:127]; accumulators in VGPRs (unified file).
#define ACLOB \
  "a0","a1","a2","a3","a4","a5","a6","a7","a8","a9","a10","a11","a12","a13","a14","a15", \
  "a16","a17","a18","a19","a20","a21","a22","a23","a24","a25","a26","a27","a28","a29","a30","a31", \
  "a32","a33","a34","a35","a36","a37","a38","a39","a40","a41","a42","a43","a44","a45","a46","a47", \
  "a48","a49","a50","a51","a52","a53","a54","a55","a56","a57","a58","a59","a60","a61","a62","a63", \
  "a64","a65","a66","a67","a68","a69","a70","a71","a72","a73","a74","a75","a76","a77","a78","a79", \
  "a80","a81","a82","a83","a84","a85","a86","a87","a88","a89","a90","a91","a92","a93","a94","a95", \
  "a96","a97","a98","a99","a100","a101","a102","a103","a104","a105","a106","a107","a108","a109","a110","a111", \
  "a112","a113","a114","a115","a116","a117","a118","a119","a120","a121","a122","a123","a124","a125","a126","a127"

#define LF8(A0,A1, U, KT) do { \
  f32x2 _t = *(const f32x2*)(whh8 + (size_t)(((U) >> 1) * 256 + wid * 32 + ((U) & 1) * 16 + l16) * 256 + (KT) * 32 + quad * 8); \
  asm volatile("v_accvgpr_write_b32 a" #A0 ", %0\n\t" \
               "v_accvgpr_write_b32 a" #A1 ", %1" \
               :: "v"(_t[0]), "v"(_t[1]) : "a" #A0, "a" #A1); } while (0)

#define LFN(A0,A1,A2,A3, TC, KT) do { \
  f32x4 _t = *(const f32x4*)(whh16 + (size_t)(512 + wid * 32 + (TC) * 16 + l16) * 256 + (KT) * 32 + quad * 8); \
  asm volatile("v_accvgpr_write_b32 a" #A0 ", %0\n\t" \
               "v_accvgpr_write_b32 a" #A1 ", %1\n\t" \
               "v_accvgpr_write_b32 a" #A2 ", %2\n\t" \
               "v_accvgpr_write_b32 a" #A3 ", %3" \
               :: "v"(_t[0]), "v"(_t[1]), "v"(_t[2]), "v"(_t[3]) \
               : "a" #A0, "a" #A1, "a" #A2, "a" #A3); } while (0)

// fp8 gate MFMA groups: accumulators %[aR0],%[aR1],%[aZ0],%[aZ1] (VGPR quads)
#define FP8GZ(P, F0,F1,F2,F3) \
  "v_mfma_f32_16x16x32_fp8_fp8 %[aR0], " P ", a[" F0 "], %[zq]\n\t" \
  "v_mfma_f32_16x16x32_fp8_fp8 %[aR1], " P ", a[" F1 "], %[zq]\n\t" \
  "v_mfma_f32_16x16x32_fp8_fp8 %[aZ0], " P ", a[" F2 "], %[zq]\n\t" \
  "v_mfma_f32_16x16x32_fp8_fp8 %[aZ1], " P ", a[" F3 "], %[zq]\n\t"

#define FP8G(P, F0,F1,F2,F3) \
  "v_mfma_f32_16x16x32_fp8_fp8 %[aR0], " P ", a[" F0 "], %[aR0]\n\t" \
  "v_mfma_f32_16x16x32_fp8_fp8 %[aR1], " P ", a[" F1 "], %[aR1]\n\t" \
  "v_mfma_f32_16x16x32_fp8_fp8 %[aZ0], " P ", a[" F2 "], %[aZ0]\n\t" \
  "v_mfma_f32_16x16x32_fp8_fp8 %[aZ1], " P ", a[" F3 "], %[aZ1]\n\t"

#define F16GZ(Q, G0,G1) \
  "v_mfma_f32_16x16x32_f16 %[aN0], " Q ", a[" G0 "], %[zq]\n\t" \
  "v_mfma_f32_16x16x32_f16 %[aN1], " Q ", a[" G1 "], %[zq]\n\t"

#define F16G(Q, G0,G1) \
  "v_mfma_f32_16x16x32_f16 %[aN0], " Q ", a[" G0 "], %[aN0]\n\t" \
  "v_mfma_f32_16x16x32_f16 %[aN1], " Q ", a[" G1 "], %[aN1]\n\t"

__global__ __launch_bounds__(512, 2) void gru_kernel(const f16* __restrict__ gi,
                                                     const f16* __restrict__ whh16,
                                                     const uint8_t* __restrict__ whh8,
                                                     const float* __restrict__ b_hh,
                                                     const float* __restrict__ W_out,
                                                     const float* __restrict__ b_out,
                                                     float* __restrict__ out) {
    __shared__ __align__(16) f16 hbufF[2][16 * 280];      // f16 h (n-gate A + head)
    __shared__ __align__(16) uint8_t hbuf8[2][16 * 272];  // fp8 h (rz A)
    const int tid = threadIdx.x, lane = tid & 63, wid = tid >> 6;   // wid 0..7
    const int quad = lane >> 4, l16 = lane & 15;
    const int bb = blockIdx.x;

    for (int i = tid; i < 16 * 280; i += 512) hbufF[1][i] = (f16)0.0f;
    for (int i = tid; i < 16 * 272; i += 512) hbuf8[1][i] = 0;

    LF8(0,1, 0,0);   LF8(2,3, 0,1);   LF8(4,5, 0,2);   LF8(6,7, 0,3);
    LF8(8,9, 0,4);   LF8(10,11, 0,5); LF8(12,13, 0,6); LF8(14,15, 0,7);
    LF8(16,17, 1,0); LF8(18,19, 1,1); LF8(20,21, 1,2); LF8(22,23, 1,3);
    LF8(24,25, 1,4); LF8(26,27, 1,5); LF8(28,29, 1,6); LF8(30,31, 1,7);
    LF8(32,33, 2,0); LF8(34,35, 2,1); LF8(36,37, 2,2); LF8(38,39, 2,3);
    LF8(40,41, 2,4); LF8(42,43, 2,5); LF8(44,45, 2,6); LF8(46,47, 2,7);
    LF8(48,49, 3,0); LF8(50,51, 3,1); LF8(52,53, 3,2); LF8(54,55, 3,3);
    LF8(56,57, 3,4); LF8(58,59, 3,5); LF8(60,61, 3,6); LF8(62,63, 3,7);
    LFN(64,65,66,67,   0,0); LFN(68,69,70,71,   0,1); LFN(72,73,74,75,   0,2); LFN(76,77,78,79,   0,3);
    LFN(80,81,82,83,   0,4); LFN(84,85,86,87,   0,5); LFN(88,89,90,91,   0,6); LFN(92,93,94,95,   0,7);
    LFN(96,97,98,99,   1,0); LFN(100,101,102,103, 1,1); LFN(104,105,106,107, 1,2); LFN(108,109,110,111, 1,3);
    LFN(112,113,114,115, 1,4); LFN(116,117,118,119, 1,5); LFN(120,121,122,123, 1,6); LFN(124,125,126,127, 1,7);

    const float C2 = 2.8853900817779268f;   // 2*log2e
    float bhn[2];
#pragma unroll
    for (int tc = 0; tc < 2; tc++) bhn[tc] = C2 * b_hh[512 + wid * 32 + tc * 16 + l16];
    float hm[2][4];
#pragma unroll
    for (int tc = 0; tc < 2; tc++)
#pragma unroll
        for (int rr = 0; rr < 4; rr++) hm[tc][rr] = 0.f;

    uint32_t aF0 = (uint32_t)(uintptr_t)(__attribute__((address_space(3))) const void*)
                       (&hbufF[0][l16 * 280 + quad * 8]);
    uint32_t aF1 = (uint32_t)(uintptr_t)(__attribute__((address_space(3))) const void*)
                       (&hbufF[1][l16 * 280 + quad * 8]);
    uint32_t a80 = (uint32_t)(uintptr_t)(__attribute__((address_space(3))) const void*)
                       (&hbuf8[0][l16 * 272 + quad * 8]);
    uint32_t a81 = (uint32_t)(uintptr_t)(__attribute__((address_space(3))) const void*)
                       (&hbuf8[1][l16 * 272 + quad * 8]);

    // coalesced gi: per (t,bb) slab = 12288 f16; chunk u at u*2048; thread at tid*4
    const size_t lanebase = (size_t)bb * 12288 + (size_t)tid * 4;
    f16x4 gcur[6];
#pragma unroll
    for (int u = 0; u < 6; u++)
        gcur[u] = *(const f16x4*)(gi + lanebase + u * 2048);

    const f32x4 zq = (f32x4){0.f, 0.f, 0.f, 0.f};

    BAR_LDS();

    for (int t = 0; t < 31; t++) {
        const uint32_t a8 = (t & 1) ? a80 : a81;
        const uint32_t aF = (t & 1) ? aF0 : aF1;
        f32x4 aR0, aR1, aZ0, aZ1, aN0, aN1;
        f32x2 p0, p1, p2;
        f32x4 q0, q1, q2;
        asm volatile(
            "s_setprio 1\n\t"
            "ds_read_b64  %[p0], %[a8] offset:0\n\t"
            "ds_read_b128 %[q0], %[aF] offset:0\n\t"
            "ds_read_b64  %[p1], %[a8] offset:32\n\t"
            "ds_read_b128 %[q1], %[aF] offset:64\n\t"
            "ds_read_b64  %[p2], %[a8] offset:64\n\t"
            "ds_read_b128 %[q2], %[aF] offset:128\n\t"
            "s_waitcnt lgkmcnt(5)\n\t"
            FP8GZ("%[p0]", "0:1","16:17","32:33","48:49")
            "ds_read_b64  %[p0], %[a8] offset:96\n\t"
            "s_waitcnt lgkmcnt(5)\n\t"
            F16GZ("%[q0]", "64:67","96:99")
            "ds_read_b128 %[q0], %[aF] offset:192\n\t"
            "s_waitcnt lgkmcnt(5)\n\t"
            FP8G("%[p1]", "2:3","18:19","34:35","50:51")
            "ds_read_b64  %[p1], %[a8] offset:128\n\t"
            "s_waitcnt lgkmcnt(5)\n\t"
            F16G("%[q1]", "68:71","100:103")
            "ds_read_b128 %[q1], %[aF] offset:256\n\t"
            "s_waitcnt lgkmcnt(5)\n\t"
            FP8G("%[p2]", "4:5","20:21","36:37","52:53")
            "ds_read_b64  %[p2], %[a8] offset:160\n\t"
            "s_waitcnt lgkmcnt(5)\n\t"
            F16G("%[q2]", "72:75","104:107")
            "ds_read_b128 %[q2], %[aF] offset:320\n\t"
            "s_waitcnt lgkmcnt(5)\n\t"
            FP8G("%[p0]", "6:7","22:23","38:39","54:55")
            "ds_read_b64  %[p0], %[a8] offset:192\n\t"
            "s_waitcnt lgkmcnt(5)\n\t"
            F16G("%[q0]", "76:79","108:111")
            "ds_read_b128 %[q0], %[aF] offset:384\n\t"
            "s_waitcnt lgkmcnt(5)\n\t"
            FP8G("%[p1]", "8:9","24:25","40:41","56:57")
            "ds_read_b64  %[p1], %[a8] offset:224\n\t"
            "s_waitcnt lgkmcnt(5)\n\t"
            F16G("%[q1]", "80:83","112:115")
            "ds_read_b128 %[q1], %[aF] offset:448\n\t"
            "s_waitcnt lgkmcnt(5)\n\t"
            FP8G("%[p2]", "10:11","26:27","42:43","58:59")
            "s_waitcnt lgkmcnt(4)\n\t"
            F16G("%[q2]", "84:87","116:119")
            "s_waitcnt lgkmcnt(3)\n\t"
            FP8G("%[p0]", "12:13","28:29","44:45","60:61")
            "s_waitcnt lgkmcnt(2)\n\t"
            F16G("%[q0]", "88:91","120:123")
            "s_waitcnt lgkmcnt(1)\n\t"
            FP8G("%[p1]", "14:15","30:31","46:47","62:63")
            "s_waitcnt lgkmcnt(0)\n\t"
            F16G("%[q1]", "92:95","124:127")
            "s_setprio 0\n\t"
            "s_nop 7\n\ts_nop 7"
            : [aR0]"=&v"(aR0), [aR1]"=&v"(aR1), [aZ0]"=&v"(aZ0), [aZ1]"=&v"(aZ1),
              [aN0]"=&v"(aN0), [aN1]"=&v"(aN1),
              [p0]"=&v"(p0), [p1]"=&v"(p1), [p2]"=&v"(p2),
              [q0]"=&v"(q0), [q1]"=&v"(q1), [q2]"=&v"(q2)
            : [a8]"v"(a8), [aF]"v"(aF), [zq]"v"(zq)
            : ACLOB);

        // gate math (exp2 form): accR/accZ are rz matmul (x1/16), accN is n matmul
        f16* hdF = hbufF[t & 1];
        uint8_t* hd8 = hbuf8[t & 1];
        const float C1N16 = -0.09016844005556021f;   // -log2e/16
#pragma unroll
        for (int tc = 0; tc < 2; tc++) {
            const int hcx = wid * 32 + tc * 16 + l16;
            const f32x4 vR = tc ? aR1 : aR0;
            const f32x4 vZ = tc ? aZ1 : aZ0;
            const f32x4 vN = tc ? aN1 : aN0;
#pragma unroll
            for (int rr = 0; rr < 4; rr++) {
                float rg = frcp(1.f + fexp2(fmaf(C1N16, vR[rr], (float)gcur[tc][rr])));
                float zg = frcp(1.f + fexp2(fmaf(C1N16, vZ[rr], (float)gcur[2 + tc][rr])));
                float t2 = fmaf(rg, fmaf(C2, vN[rr], bhn[tc]), (float)gcur[4 + tc][rr]);
                float e2 = fexp2(t2);
                float ng = fmaf(-2.f, frcp(e2 + 1.f), 1.f);   // tanh
                float h  = fmaf(zg, hm[tc][rr] - ng, ng);     // (1-z)n + z*h
                hm[tc][rr] = h;
                hdF[(quad * 4 + rr) * 280 + hcx] = (f16)h;
                int pk = __builtin_amdgcn_cvt_pk_fp8_f32(h, h, 0, false);
                hd8[(quad * 4 + rr) * 272 + hcx] = (uint8_t)pk;
            }
        }
        // prefetch gi for t+1 (registers; survives lgkm-only barrier)
        {
            int tn = (t < 30) ? t + 1 : 30;
            const f16* gsrc = gi + (size_t)tn * 98304 + lanebase;
#pragma unroll
            for (int u = 0; u < 6; u++)
                gcur[u] = *(const f16x4*)(gsrc + u * 2048);
        }
        BAR_LDS();
    }
    // output head: final h in hbufF[0]
    if (tid < 160) {
        int r = tid / 10, oc = tid - r * 10;
        const f16* hfin = hbufF[0];
        float s = b_out[oc];
        for (int k = 0; k < 256; k++) s += (float)hfin[r * 280 + k] * W_out[oc * 256 + k];
        out[(bb * 16 + r) * 10 + oc] = frcp(1.f + __expf(-s));
    }
}

// ---------------------------------------------------------------- launch
extern "C" void kernel_launch(void* const* d_in, const int* in_sizes, int n_in,
                              void* d_out, int out_size, void* d_ws, size_t ws_size,
                              hipStream_t stream) {
    const float* x     = (const float*)d_in[0];
    const float* W_aug = (const float*)d_in[1];
    // d_in[2] = b_aug — cancels in dx, unused
    const float* W_ih  = (const float*)d_in[3];
    const float* W_hh  = (const float*)d_in[4];
    const float* b_ih  = (const float*)d_in[5];
    const float* b_hh  = (const float*)d_in[6];
    const float* W_out = (const float*)d_in[7];
    const float* b_out = (const float*)d_in[8];
    float* out = (float*)d_out;

    char* ws = (char*)d_ws;
    const size_t SIG_BYTES  = (size_t)3968 * 2240 * 2;           // 17,776,640
    const size_t WIH_BYTES  = (size_t)768 * 2240 * 2;            //  3,440,640
    const size_t WHH_BYTES  = (size_t)768 * 256 * 2;             //    393,216
    const size_t WHH8_BYTES = (size_t)512 * 256;                 //    131,072
    const size_t GI_BYTES   = (size_t)31 * 8 * 6 * 512 * 4 * 2;  //  6,094,848
    if (ws_size < SIG_BYTES + WIH_BYTES + WHH_BYTES + WHH8_BYTES + GI_BYTES) return;
    f16* sig16    = (f16*)ws;
    f16* wih16    = (f16*)(ws + SIG_BYTES);
    f16* whh16    = (f16*)(ws + SIG_BYTES + WIH_BYTES);
    uint8_t* whh8 = (uint8_t*)(ws + SIG_BYTES + WIH_BYTES + WHH_BYTES);
    f16* giw      = (f16*)(ws + SIG_BYTES + WIH_BYTES + WHH_BYTES + WHH8_BYTES);

    hipLaunchKernelGGL(prep_kernel, dim3(2920), dim3(256), 0, stream,
                       x, W_aug, W_ih, W_hh, sig16, wih16, whh16, whh8);
    hipLaunchKernelGGL(gemm_kernel, dim3(372), dim3(256), 0, stream,
                       sig16, wih16, b_ih, b_hh, giw);
    hipLaunchKernelGGL(gru_kernel, dim3(8), dim3(512), 0, stream,
                       giw, whh16, whh8, b_hh, W_out, b_out, out);
}

// Round 8
// 199.588 us; speedup vs baseline: 1.1029x; 1.0027x over previous
//
#include <hip/hip_runtime.h>
#include <hip/hip_bf16.h>
#include <stdint.h>

// Problem constants
// B=128 STREAM=512 IN_CH=4 EXTRA=5 GROUPS=2 DEPTH=3 STEP=16 LENGTH=32 RNN=256 OUT=10
// C=10 SIG_C=1110 W=31 F=2220, padded K = 2240, GEMM M = 31*128 = 3968, N = 768
// gi layout (f16, COALESCED): chunk u of thread gtid at step (t,bb):
//   f16 offset = ((t*8+bb)*6 + u)*2048 + gtid*4,  u = gs*2+gtc in [0,6)
// gi VALUES pre-scaled for exp2-based gate math:
//   r,z chunks: -log2e*(gemm + b_ih + b_hh);  n chunks: 2*log2e*(gemm + b_ih)
// GEMM (round 8): XCD-affinity block mapping. Round-5 fused measurement pinned
//   gemm at ~60us; FETCH_SIZE showed HBM sees only unique bytes, so the cost is
//   L3->L2 re-read traffic (A x6 across XCDs ~106MB). Grid padded to 384 =
//   8 XCD x (8 mb x 6 nb); dispatch round-robins blockIdx%8 across XCDs, so
//   each XCD owns 8 consecutive mb strips x all 6 nb -> same-t blocks share
//   one L2; A pulled from L3 once per strip (17.8MB total), B once per XCD.
//   Tile structure itself unchanged from round 7 (64x128, 6-buf 5-deep async).
// prep: unchanged (LDS-staged coalesced row store).
// GRU: unchanged (W_hh pinned in AGPRs, VGPR accumulators, exp2 gate math).

typedef _Float16 f16;
typedef f16  f16x2 __attribute__((ext_vector_type(2)));
typedef f16  f16x4 __attribute__((ext_vector_type(4)));
typedef f16  f16x8 __attribute__((ext_vector_type(8)));
typedef float f32x2 __attribute__((ext_vector_type(2)));
typedef float f32x4 __attribute__((ext_vector_type(4)));

#define ASYNC16(gp, lp) __builtin_amdgcn_global_load_lds( \
    (const __attribute__((address_space(1))) void*)(gp),  \
    (__attribute__((address_space(3))) void*)(lp), 16, 0, 0)

#define BAR_LDS() do { asm volatile("s_waitcnt lgkmcnt(0)" ::: "memory"); \
                       __builtin_amdgcn_s_barrier();                      \
                       asm volatile("" ::: "memory"); } while (0)

__device__ __forceinline__ float fexp2(float x) {
    float r; asm("v_exp_f32 %0, %1" : "=v"(r) : "v"(x)); return r;
}
__device__ __forceinline__ float frcp(float x) {
    float r; asm("v_rcp_f32 %0, %1" : "=v"(r) : "v"(x)); return r;
}

// ---------------------------------------------------------------- K0: prep
// blocks [0,840):    W_ih f32 -> f16 (pad 2220->2240), 8 elems/thread
// blocks [840,936):  W_hh f32 -> f16 (all) + fp8*16 (r,z rows), 8 elems/thread
// blocks [936,2920): signature chains, 4/block; LDS-staged coalesced row store
__global__ __launch_bounds__(256) void prep_kernel(const float* __restrict__ x,
                                                   const float* __restrict__ W_aug,
                                                   const float* __restrict__ Wih,
                                                   const float* __restrict__ Whh,
                                                   f16* __restrict__ sig16,
                                                   f16* __restrict__ wih16,
                                                   f16* __restrict__ whh16,
                                                   uint8_t* __restrict__ whh8) {
    __shared__ float dxs[4][31][10];
    __shared__ f16 srow[4][1112];                  // per-chain staging (1110 + pad)
    const int tid = threadIdx.x;
    if (blockIdx.x < 840) {
        int c = blockIdx.x * 256 + tid;          // chunk 0..215039
        int r = c / 280, kc = (c - r * 280) * 8;
        const float* src = Wih + (size_t)r * 2220 + kc;
        f16x8 o;
        if (kc + 8 <= 2220) {
            float4 v0 = *(const float4*)(src);
            float4 v1 = *(const float4*)(src + 4);
            o[0]=(f16)v0.x; o[1]=(f16)v0.y; o[2]=(f16)v0.z; o[3]=(f16)v0.w;
            o[4]=(f16)v1.x; o[5]=(f16)v1.y; o[6]=(f16)v1.z; o[7]=(f16)v1.w;
        } else {
#pragma unroll
            for (int j = 0; j < 8; j++)
                o[j] = (f16)((kc + j < 2220) ? src[j] : 0.0f);
        }
        *(f16x8*)(wih16 + (size_t)r * 2240 + kc) = o;
        return;
    }
    if (blockIdx.x < 936) {
        int c2 = ((int)blockIdx.x - 840) * 256 + tid;    // 0..24575
        int j8 = c2 * 8;
        float w[8];
        {
            float4 v0 = *(const float4*)(Whh + j8);
            float4 v1 = *(const float4*)(Whh + j8 + 4);
            w[0]=v0.x; w[1]=v0.y; w[2]=v0.z; w[3]=v0.w;
            w[4]=v1.x; w[5]=v1.y; w[6]=v1.z; w[7]=v1.w;
        }
        f16x8 o;
#pragma unroll
        for (int j = 0; j < 8; j++) o[j] = (f16)w[j];
        *(f16x8*)(whh16 + j8) = o;
        if (j8 < 131072) {                       // r,z gate rows -> fp8 e4m3 (x16)
            uint32_t p01 = (uint32_t)__builtin_amdgcn_cvt_pk_fp8_f32(w[0]*16.f, w[1]*16.f, 0, false) & 0xffffu;
            uint32_t p23 = (uint32_t)__builtin_amdgcn_cvt_pk_fp8_f32(w[2]*16.f, w[3]*16.f, 0, false) & 0xffffu;
            uint32_t p45 = (uint32_t)__builtin_amdgcn_cvt_pk_fp8_f32(w[4]*16.f, w[5]*16.f, 0, false) & 0xffffu;
            uint32_t p67 = (uint32_t)__builtin_amdgcn_cvt_pk_fp8_f32(w[6]*16.f, w[7]*16.f, 0, false) & 0xffffu;
            uint2 st = make_uint2(p01 | (p23 << 16), p45 | (p67 << 16));
            *(uint2*)(whh8 + j8) = st;
        }
        return;
    }
    // ---- signature chains (block-uniform branch; __syncthreads safe)
    const int sub = tid >> 6, t64 = tid & 63;
    const int cid = ((int)blockIdx.x - 936) * 4 + sub;   // 0..7935
    const int w = cid % 31;
    const int bg = cid / 31;
    const int b = bg >> 1, g = bg & 1;
    if (t64 < 31) {
        int s = w * 16 + t64;
        const float4 x0 = *(const float4*)(x + ((size_t)b * 512 + s) * 4);
        const float4 x1 = *(const float4*)(x + ((size_t)b * 512 + s + 1) * 4);
        float d0 = x1.x - x0.x, d1 = x1.y - x0.y, d2 = x1.z - x0.z, d3 = x1.w - x0.w;
        dxs[sub][t64][0] = d0; dxs[sub][t64][1] = d1;
        dxs[sub][t64][2] = d2; dxs[sub][t64][3] = d3;
        dxs[sub][t64][4] = 1.0f / 511.0f;
#pragma unroll
        for (int e = 0; e < 5; e++) {
            const float* wa = W_aug + (g * 5 + e) * 4;
            dxs[sub][t64][5 + e] = d0 * wa[0] + d1 * wa[1] + d2 * wa[2] + d3 * wa[3];
        }
    }
    __syncthreads();
    size_t base = ((size_t)(w * 128 + b)) * 2240 + (size_t)g * 1110;
    if (t64 < 50) {
        int p0 = 2 * t64, p1 = p0 + 1;
        int i0 = p0 / 10, j0 = p0 % 10, j1 = j0 + 1;   // p0 even -> j1 <= 9
        // loop-invariant LDS pointers: dynamic column index resolved ONCE
        const float* dz  = &dxs[sub][0][0];
        const float* pI  = dz + i0;
        const float* pJ0 = dz + j0;
        const float* pJ1 = dz + j1;
        float s3a[10], s3b[10];                        // constant-indexed -> registers
#pragma unroll
        for (int k = 0; k < 10; k++) { s3a[k] = 0.f; s3b[k] = 0.f; }
        float s2a = 0.f, s2b = 0.f, s1 = 0.f;
        for (int l = 0; l < 31; l++) {
            const float* row = dz + l * 10;
            float di  = pI[l * 10];
            float dj0 = pJ0[l * 10];
            float dj1 = pJ1[l * 10];
            float t0 = s1 + di * (1.0f / 3.0f);
            float a0 = s2a + t0 * (0.5f * dj0);
            float a1 = s2b + t0 * (0.5f * dj1);
#pragma unroll
            for (int k = 0; k < 10; k++) {
                float dk = row[k];
                s3a[k] += a0 * dk;
                s3b[k] += a1 * dk;
            }
            float u = s1 + 0.5f * di;
            s2a += u * dj0;
            s2b += u * dj1;
            s1 += di;
        }
        // stage into LDS (scatter is free there); global store happens coalesced below
        *(f16x2*)&srow[sub][10 + p0] = (f16x2){(f16)s2a, (f16)s2b};
#pragma unroll
        for (int k = 0; k < 5; k++)
            *(f16x2*)&srow[sub][110 + p0 * 10 + 2 * k] =
                (f16x2){(f16)s3a[2 * k], (f16)s3a[2 * k + 1]};
#pragma unroll
        for (int k = 0; k < 5; k++)
            *(f16x2*)&srow[sub][110 + p1 * 10 + 2 * k] =
                (f16x2){(f16)s3b[2 * k], (f16)s3b[2 * k + 1]};
    } else if (t64 < 60) {
        int c = t64 - 50;
        const float* pc = &dxs[sub][0][0] + c;
        float s = 0.f;
        for (int l = 0; l < 31; l++) s += pc[l * 10];
        srow[sub][c] = (f16)s;
    }
    __syncthreads();
    // coalesced copy-out: lane j writes 4B at base*2 + 4j (contiguous across lanes)
    for (int j = t64; j < 555; j += 64)
        *(f16x2*)(sig16 + base + 2 * j) = *(const f16x2*)&srow[sub][2 * j];
    if (g == 1 && t64 < 10)
        *(f16x2*)(sig16 + ((size_t)(w * 128 + b)) * 2240 + 2220 + 2 * t64) =
            (f16x2){(f16)0.0f, (f16)0.0f};
}

// ---------------------------------------------------------------- K2: gi = sig @ W_ih.T + biases (f16, coalesced GRU layout)
// 64x128 tile, XCD-affinity mapping (384-slot grid), 6-buffer 5-deep pipeline.
__global__ __launch_bounds__(256) void gemm_kernel(const f16* __restrict__ A,     // 3968 x 2240
                                                   const f16* __restrict__ Bw,    // 768 x 2240 f16
                                                   const float* __restrict__ bias,
                                                   const float* __restrict__ bhh,
                                                   f16* __restrict__ Cgi) {
    // XCD-affinity map: dispatch round-robins blockIdx%8 across the 8 XCDs.
    // XCD x owns mb in [8x, 8x+8) x all 6 nb -> same-t blocks share one L2;
    // A strip fetched from L3 once per XCD (2.3MB), B once per XCD (3.4MB).
    const int lin = blockIdx.x;          // 384 = 8 XCD x (8 mb x 6 nb)
    const int xcd = lin & 7;
    const int k9  = lin >> 3;            // 0..47
    const int mb  = xcd * 8 + (k9 & 7);  // 0..63
    if (mb >= 62) return;                // mb 62,63 dead (M = 62 x 64 rows)
    const int nb  = k9 >> 3;             // 0..5
    const int t = mb >> 1, half = mb & 1;
    __shared__ __align__(16) f16 As[6][64 * 32];    // 24 KB
    __shared__ __align__(16) f16 Bs[6][128 * 32];   // 48 KB  (total 72 KB -> 2 blocks/CU)
    const int tid = threadIdx.x, lane = tid & 63, wid = tid >> 6;   // wid 0..3
    const int l16 = lane & 15, quad = lane >> 4;
    const int lrow = lane >> 2, lk = lane & 3;
    const int Nbase = nb * 128;
    // per-wave staging: A rows [wid*16,+16), B rows [wid*32,+32)
    const f16* gaA  = A  + (size_t)(t * 128 + half * 64 + wid * 16 + lrow) * 2240 + lk * 8;
    const f16* gbB0 = Bw + (size_t)(Nbase + wid * 32 + lrow) * 2240 + lk * 8;
    const f16* gbB1 = Bw + (size_t)(Nbase + wid * 32 + 16 + lrow) * 2240 + lk * 8;

#define GISSUE(KT, BUF) do { \
        int _k0 = (KT) * 32; \
        ASYNC16(gaA  + _k0, &As[BUF][(wid * 16) * 32]); \
        ASYNC16(gbB0 + _k0, &Bs[BUF][(wid * 32) * 32]); \
        ASYNC16(gbB1 + _k0, &Bs[BUF][(wid * 32 + 16) * 32]); } while (0)

#define GCOMPUTE(BUF) do { \
        f16x8 af[4], bf[2]; \
        _Pragma("unroll") \
        for (int mt = 0; mt < 4; mt++) \
            af[mt] = *(const f16x8*)&As[BUF][(mt * 16 + l16) * 32 + quad * 8]; \
        _Pragma("unroll") \
        for (int nt = 0; nt < 2; nt++) \
            bf[nt] = *(const f16x8*)&Bs[BUF][(wid * 32 + nt * 16 + l16) * 32 + quad * 8]; \
        _Pragma("unroll") \
        for (int mt = 0; mt < 4; mt++) \
            _Pragma("unroll") \
            for (int nt = 0; nt < 2; nt++) \
                acc[mt][nt] = __builtin_amdgcn_mfma_f32_16x16x32_f16(af[mt], bf[nt], acc[mt][nt], 0, 0, 0); } while (0)

    f32x4 acc[4][2];
#pragma unroll
    for (int mt = 0; mt < 4; mt++)
#pragma unroll
        for (int nt = 0; nt < 2; nt++) acc[mt][nt] = (f32x4){0.f, 0.f, 0.f, 0.f};

    // prologue: 5 tiles in flight (15 loads per wave)
    GISSUE(0, 0); GISSUE(1, 1); GISSUE(2, 2); GISSUE(3, 3); GISSUE(4, 4);
    for (int kt = 0; kt < 65; kt++) {
        // per-wave: wait only tile kt (oldest 3 of 15); 4 tiles stay in flight
        asm volatile("s_waitcnt vmcnt(12) lgkmcnt(0)\n\ts_barrier" ::: "memory");
        GISSUE(kt + 5, (kt + 5) % 6);
        GCOMPUTE(kt % 6);
    }
    // drain: tiles 65..69 all in flight; one full wait, then compute
    asm volatile("s_waitcnt vmcnt(0) lgkmcnt(0)\n\ts_barrier" ::: "memory");
    GCOMPUTE(5); GCOMPUTE(0); GCOMPUTE(1); GCOMPUTE(2); GCOMPUTE(3);   // 65..69 mod 6

    // epilogue: coalesced chunk layout + exp2 pre-scaling
    const float NEG_LOG2E = -1.4426950408889634f;
    const float TWO_LOG2E =  2.8853900817779268f;
#pragma unroll
    for (int mt = 0; mt < 4; mt++) {
        const int bbv = half * 4 + mt;
#pragma unroll
        for (int nt = 0; nt < 2; nt++) {
            int col = Nbase + wid * 32 + nt * 16 + l16;
            float bvv = bias[col] + (col < 512 ? bhh[col] : 0.0f);   // fold b_hh into r,z
            float scl = (col < 512) ? NEG_LOG2E : TWO_LOG2E;
            int gs = col >> 8, hcc = col & 255;
            int gw = hcc >> 5, gtc = (hcc >> 4) & 1, gl = hcc & 15;
            int u = gs * 2 + gtc;
            int gtid = gw * 64 + quad * 16 + gl;
            size_t off = ((size_t)((t * 8 + bbv) * 6 + u)) * 2048 + (size_t)gtid * 4;
            f16x4 st;
#pragma unroll
            for (int rr = 0; rr < 4; rr++) st[rr] = (f16)((acc[mt][nt][rr] + bvv) * scl);
            *(f16x4*)(Cgi + off) = st;
        }
    }
#undef GISSUE
#undef GCOMPUTE
}

// ---------------------------------------------------------------- K3: GRU scan
// W_hh fragments pinned a[0:127]; accumulators in VGPRs (unified file).
#define ACLOB \
  "a0","a1","a2","a3","a4","a5","a6","a7","a8","a9","a10","a11","a12","a13","a14","a15", \
  "a16","a17","a18","a19","a20","a21","a22","a23","a24","a25","a26","a27","a28","a29","a30","a31", \
  "a32","a33","a34","a35","a36","a37","a38","a39","a40","a41","a42","a43","a44","a45","a46","a47", \
  "a48","a49","a50","a51","a52","a53","a54","a55","a56","a57","a58","a59","a60","a61","a62","a63", \
  "a64","a65","a66","a67","a68","a69","a70","a71","a72","a73","a74","a75","a76","a77","a78","a79", \
  "a80","a81","a82","a83","a84","a85","a86","a87","a88","a89","a90","a91","a92","a93","a94","a95", \
  "a96","a97","a98","a99","a100","a101","a102","a103","a104","a105","a106","a107","a108","a109","a110","a111", \
  "a112","a113","a114","a115","a116","a117","a118","a119","a120","a121","a122","a123","a124","a125","a126","a127"

#define LF8(A0,A1, U, KT) do { \
  f32x2 _t = *(const f32x2*)(whh8 + (size_t)(((U) >> 1) * 256 + wid * 32 + ((U) & 1) * 16 + l16) * 256 + (KT) * 32 + quad * 8); \
  asm volatile("v_accvgpr_write_b32 a" #A0 ", %0\n\t" \
               "v_accvgpr_write_b32 a" #A1 ", %1" \
               :: "v"(_t[0]), "v"(_t[1]) : "a" #A0, "a" #A1); } while (0)

#define LFN(A0,A1,A2,A3, TC, KT) do { \
  f32x4 _t = *(const f32x4*)(whh16 + (size_t)(512 + wid * 32 + (TC) * 16 + l16) * 256 + (KT) * 32 + quad * 8); \
  asm volatile("v_accvgpr_write_b32 a" #A0 ", %0\n\t" \
               "v_accvgpr_write_b32 a" #A1 ", %1\n\t" \
               "v_accvgpr_write_b32 a" #A2 ", %2\n\t" \
               "v_accvgpr_write_b32 a" #A3 ", %3" \
               :: "v"(_t[0]), "v"(_t[1]), "v"(_t[2]), "v"(_t[3]) \
               : "a" #A0, "a" #A1, "a" #A2, "a" #A3); } while (0)

// fp8 gate MFMA groups: accumulators %[aR0],%[aR1],%[aZ0],%[aZ1] (VGPR quads)
#define FP8GZ(P, F0,F1,F2,F3) \
  "v_mfma_f32_16x16x32_fp8_fp8 %[aR0], " P ", a[" F0 "], %[zq]\n\t" \
  "v_mfma_f32_16x16x32_fp8_fp8 %[aR1], " P ", a[" F1 "], %[zq]\n\t" \
  "v_mfma_f32_16x16x32_fp8_fp8 %[aZ0], " P ", a[" F2 "], %[zq]\n\t" \
  "v_mfma_f32_16x16x32_fp8_fp8 %[aZ1], " P ", a[" F3 "], %[zq]\n\t"

#define FP8G(P, F0,F1,F2,F3) \
  "v_mfma_f32_16x16x32_fp8_fp8 %[aR0], " P ", a[" F0 "], %[aR0]\n\t" \
  "v_mfma_f32_16x16x32_fp8_fp8 %[aR1], " P ", a[" F1 "], %[aR1]\n\t" \
  "v_mfma_f32_16x16x32_fp8_fp8 %[aZ0], " P ", a[" F2 "], %[aZ0]\n\t" \
  "v_mfma_f32_16x16x32_fp8_fp8 %[aZ1], " P ", a[" F3 "], %[aZ1]\n\t"

#define F16GZ(Q, G0,G1) \
  "v_mfma_f32_16x16x32_f16 %[aN0], " Q ", a[" G0 "], %[zq]\n\t" \
  "v_mfma_f32_16x16x32_f16 %[aN1], " Q ", a[" G1 "], %[zq]\n\t"

#define F16G(Q, G0,G1) \
  "v_mfma_f32_16x16x32_f16 %[aN0], " Q ", a[" G0 "], %[aN0]\n\t" \
  "v_mfma_f32_16x16x32_f16 %[aN1], " Q ", a[" G1 "], %[aN1]\n\t"

__global__ __launch_bounds__(512, 2) void gru_kernel(const f16* __restrict__ gi,
                                                     const f16* __restrict__ whh16,
                                                     const uint8_t* __restrict__ whh8,
                                                     const float* __restrict__ b_hh,
                                                     const float* __restrict__ W_out,
                                                     const float* __restrict__ b_out,
                                                     float* __restrict__ out) {
    __shared__ __align__(16) f16 hbufF[2][16 * 280];      // f16 h (n-gate A + head)
    __shared__ __align__(16) uint8_t hbuf8[2][16 * 272];  // fp8 h (rz A)
    const int tid = threadIdx.x, lane = tid & 63, wid = tid >> 6;   // wid 0..7
    const int quad = lane >> 4, l16 = lane & 15;
    const int bb = blockIdx.x;

    for (int i = tid; i < 16 * 280; i += 512) hbufF[1][i] = (f16)0.0f;
    for (int i = tid; i < 16 * 272; i += 512) hbuf8[1][i] = 0;

    LF8(0,1, 0,0);   LF8(2,3, 0,1);   LF8(4,5, 0,2);   LF8(6,7, 0,3);
    LF8(8,9, 0,4);   LF8(10,11, 0,5); LF8(12,13, 0,6); LF8(14,15, 0,7);
    LF8(16,17, 1,0); LF8(18,19, 1,1); LF8(20,21, 1,2); LF8(22,23, 1,3);
    LF8(24,25, 1,4); LF8(26,27, 1,5); LF8(28,29, 1,6); LF8(30,31, 1,7);
    LF8(32,33, 2,0); LF8(34,35, 2,1); LF8(36,37, 2,2); LF8(38,39, 2,3);
    LF8(40,41, 2,4); LF8(42,43, 2,5); LF8(44,45, 2,6); LF8(46,47, 2,7);
    LF8(48,49, 3,0); LF8(50,51, 3,1); LF8(52,53, 3,2); LF8(54,55, 3,3);
    LF8(56,57, 3,4); LF8(58,59, 3,5); LF8(60,61, 3,6); LF8(62,63, 3,7);
    LFN(64,65,66,67,   0,0); LFN(68,69,70,71,   0,1); LFN(72,73,74,75,   0,2); LFN(76,77,78,79,   0,3);
    LFN(80,81,82,83,   0,4); LFN(84,85,86,87,   0,5); LFN(88,89,90,91,   0,6); LFN(92,93,94,95,   0,7);
    LFN(96,97,98,99,   1,0); LFN(100,101,102,103, 1,1); LFN(104,105,106,107, 1,2); LFN(108,109,110,111, 1,3);
    LFN(112,113,114,115, 1,4); LFN(116,117,118,119, 1,5); LFN(120,121,122,123, 1,6); LFN(124,125,126,127, 1,7);

    const float C2 = 2.8853900817779268f;   // 2*log2e
    float bhn[2];
#pragma unroll
    for (int tc = 0; tc < 2; tc++) bhn[tc] = C2 * b_hh[512 + wid * 32 + tc * 16 + l16];
    float hm[2][4];
#pragma unroll
    for (int tc = 0; tc < 2; tc++)
#pragma unroll
        for (int rr = 0; rr < 4; rr++) hm[tc][rr] = 0.f;

    uint32_t aF0 = (uint32_t)(uintptr_t)(__attribute__((address_space(3))) const void*)
                       (&hbufF[0][l16 * 280 + quad * 8]);
    uint32_t aF1 = (uint32_t)(uintptr_t)(__attribute__((address_space(3))) const void*)
                       (&hbufF[1][l16 * 280 + quad * 8]);
    uint32_t a80 = (uint32_t)(uintptr_t)(__attribute__((address_space(3))) const void*)
                       (&hbuf8[0][l16 * 272 + quad * 8]);
    uint32_t a81 = (uint32_t)(uintptr_t)(__attribute__((address_space(3))) const void*)
                       (&hbuf8[1][l16 * 272 + quad * 8]);

    // coalesced gi: per (t,bb) slab = 12288 f16; chunk u at u*2048; thread at tid*4
    const size_t lanebase = (size_t)bb * 12288 + (size_t)tid * 4;
    f16x4 gcur[6];
#pragma unroll
    for (int u = 0; u < 6; u++)
        gcur[u] = *(const f16x4*)(gi + lanebase + u * 2048);

    const f32x4 zq = (f32x4){0.f, 0.f, 0.f, 0.f};

    BAR_LDS();

    for (int t = 0; t < 31; t++) {
        const uint32_t a8 = (t & 1) ? a80 : a81;
        const uint32_t aF = (t & 1) ? aF0 : aF1;
        f32x4 aR0, aR1, aZ0, aZ1, aN0, aN1;
        f32x2 p0, p1, p2;
        f32x4 q0, q1, q2;
        asm volatile(
            "s_setprio 1\n\t"
            "ds_read_b64  %[p0], %[a8] offset:0\n\t"
            "ds_read_b128 %[q0], %[aF] offset:0\n\t"
            "ds_read_b64  %[p1], %[a8] offset:32\n\t"
            "ds_read_b128 %[q1], %[aF] offset:64\n\t"
            "ds_read_b64  %[p2], %[a8] offset:64\n\t"
            "ds_read_b128 %[q2], %[aF] offset:128\n\t"
            "s_waitcnt lgkmcnt(5)\n\t"
            FP8GZ("%[p0]", "0:1","16:17","32:33","48:49")
            "ds_read_b64  %[p0], %[a8] offset:96\n\t"
            "s_waitcnt lgkmcnt(5)\n\t"
            F16GZ("%[q0]", "64:67","96:99")
            "ds_read_b128 %[q0], %[aF] offset:192\n\t"
            "s_waitcnt lgkmcnt(5)\n\t"
            FP8G("%[p1]", "2:3","18:19","34:35","50:51")
            "ds_read_b64  %[p1], %[a8] offset:128\n\t"
            "s_waitcnt lgkmcnt(5)\n\t"
            F16G("%[q1]", "68:71","100:103")
            "ds_read_b128 %[q1], %[aF] offset:256\n\t"
            "s_waitcnt lgkmcnt(5)\n\t"
            FP8G("%[p2]", "4:5","20:21","36:37","52:53")
            "ds_read_b64  %[p2], %[a8] offset:160\n\t"
            "s_waitcnt lgkmcnt(5)\n\t"
            F16G("%[q2]", "72:75","104:107")
            "ds_read_b128 %[q2], %[aF] offset:320\n\t"
            "s_waitcnt lgkmcnt(5)\n\t"
            FP8G("%[p0]", "6:7","22:23","38:39","54:55")
            "ds_read_b64  %[p0], %[a8] offset:192\n\t"
            "s_waitcnt lgkmcnt(5)\n\t"
            F16G("%[q0]", "76:79","108:111")
            "ds_read_b128 %[q0], %[aF] offset:384\n\t"
            "s_waitcnt lgkmcnt(5)\n\t"
            FP8G("%[p1]", "8:9","24:25","40:41","56:57")
            "ds_read_b64  %[p1], %[a8] offset:224\n\t"
            "s_waitcnt lgkmcnt(5)\n\t"
            F16G("%[q1]", "80:83","112:115")
            "ds_read_b128 %[q1], %[aF] offset:448\n\t"
            "s_waitcnt lgkmcnt(5)\n\t"
            FP8G("%[p2]", "10:11","26:27","42:43","58:59")
            "s_waitcnt lgkmcnt(4)\n\t"
            F16G("%[q2]", "84:87","116:119")
            "s_waitcnt lgkmcnt(3)\n\t"
            FP8G("%[p0]", "12:13","28:29","44:45","60:61")
            "s_waitcnt lgkmcnt(2)\n\t"
            F16G("%[q0]", "88:91","120:123")
            "s_waitcnt lgkmcnt(1)\n\t"
            FP8G("%[p1]", "14:15","30:31","46:47","62:63")
            "s_waitcnt lgkmcnt(0)\n\t"
            F16G("%[q1]", "92:95","124:127")
            "s_setprio 0\n\t"
            "s_nop 7\n\ts_nop 7"
            : [aR0]"=&v"(aR0), [aR1]"=&v"(aR1), [aZ0]"=&v"(aZ0), [aZ1]"=&v"(aZ1),
              [aN0]"=&v"(aN0), [aN1]"=&v"(aN1),
              [p0]"=&v"(p0), [p1]"=&v"(p1), [p2]"=&v"(p2),
              [q0]"=&v"(q0), [q1]"=&v"(q1), [q2]"=&v"(q2)
            : [a8]"v"(a8), [aF]"v"(aF), [zq]"v"(zq)
            : ACLOB);

        // gate math (exp2 form): accR/accZ are rz matmul (x1/16), accN is n matmul
        f16* hdF = hbufF[t & 1];
        uint8_t* hd8 = hbuf8[t & 1];
        const float C1N16 = -0.09016844005556021f;   // -log2e/16
#pragma unroll
        for (int tc = 0; tc < 2; tc++) {
            const int hcx = wid * 32 + tc * 16 + l16;
            const f32x4 vR = tc ? aR1 : aR0;
            const f32x4 vZ = tc ? aZ1 : aZ0;
            const f32x4 vN = tc ? aN1 : aN0;
#pragma unroll
            for (int rr = 0; rr < 4; rr++) {
                float rg = frcp(1.f + fexp2(fmaf(C1N16, vR[rr], (float)gcur[tc][rr])));
                float zg = frcp(1.f + fexp2(fmaf(C1N16, vZ[rr], (float)gcur[2 + tc][rr])));
                float t2 = fmaf(rg, fmaf(C2, vN[rr], bhn[tc]), (float)gcur[4 + tc][rr]);
                float e2 = fexp2(t2);
                float ng = fmaf(-2.f, frcp(e2 + 1.f), 1.f);   // tanh
                float h  = fmaf(zg, hm[tc][rr] - ng, ng);     // (1-z)n + z*h
                hm[tc][rr] = h;
                hdF[(quad * 4 + rr) * 280 + hcx] = (f16)h;
                int pk = __builtin_amdgcn_cvt_pk_fp8_f32(h, h, 0, false);
                hd8[(quad * 4 + rr) * 272 + hcx] = (uint8_t)pk;
            }
        }
        // prefetch gi for t+1 (registers; survives lgkm-only barrier)
        {
            int tn = (t < 30) ? t + 1 : 30;
            const f16* gsrc = gi + (size_t)tn * 98304 + lanebase;
#pragma unroll
            for (int u = 0; u < 6; u++)
                gcur[u] = *(const f16x4*)(gsrc + u * 2048);
        }
        BAR_LDS();
    }
    // output head: final h in hbufF[0]
    if (tid < 160) {
        int r = tid / 10, oc = tid - r * 10;
        const f16* hfin = hbufF[0];
        float s = b_out[oc];
        for (int k = 0; k < 256; k++) s += (float)hfin[r * 280 + k] * W_out[oc * 256 + k];
        out[(bb * 16 + r) * 10 + oc] = frcp(1.f + __expf(-s));
    }
}

// ---------------------------------------------------------------- launch
extern "C" void kernel_launch(void* const* d_in, const int* in_sizes, int n_in,
                              void* d_out, int out_size, void* d_ws, size_t ws_size,
                              hipStream_t stream) {
    const float* x     = (const float*)d_in[0];
    const float* W_aug = (const float*)d_in[1];
    // d_in[2] = b_aug — cancels in dx, unused
    const float* W_ih  = (const float*)d_in[3];
    const float* W_hh  = (const float*)d_in[4];
    const float* b_ih  = (const float*)d_in[5];
    const float* b_hh  = (const float*)d_in[6];
    const float* W_out = (const float*)d_in[7];
    const float* b_out = (const float*)d_in[8];
    float* out = (float*)d_out;

    char* ws = (char*)d_ws;
    const size_t SIG_BYTES  = (size_t)3968 * 2240 * 2;           // 17,776,640
    const size_t WIH_BYTES  = (size_t)768 * 2240 * 2;            //  3,440,640
    const size_t WHH_BYTES  = (size_t)768 * 256 * 2;             //    393,216
    const size_t WHH8_BYTES = (size_t)512 * 256;                 //    131,072
    const size_t GI_BYTES   = (size_t)31 * 8 * 6 * 512 * 4 * 2;  //  6,094,848
    if (ws_size < SIG_BYTES + WIH_BYTES + WHH_BYTES + WHH8_BYTES + GI_BYTES) return;
    f16* sig16    = (f16*)ws;
    f16* wih16    = (f16*)(ws + SIG_BYTES);
    f16* whh16    = (f16*)(ws + SIG_BYTES + WIH_BYTES);
    uint8_t* whh8 = (uint8_t*)(ws + SIG_BYTES + WIH_BYTES + WHH_BYTES);
    f16* giw      = (f16*)(ws + SIG_BYTES + WIH_BYTES + WHH_BYTES + WHH8_BYTES);

    hipLaunchKernelGGL(prep_kernel, dim3(2920), dim3(256), 0, stream,
                       x, W_aug, W_ih, W_hh, sig16, wih16, whh16, whh8);
    hipLaunchKernelGGL(gemm_kernel, dim3(384), dim3(256), 0, stream,
                       sig16, wih16, b_ih, b_hh, giw);
    hipLaunchKernelGGL(gru_kernel, dim3(8), dim3(512), 0, stream,
                       giw, whh16, whh8, b_hh, W_out, b_out, out);
}

// Round 9
// 196.372 us; speedup vs baseline: 1.1209x; 1.0164x over previous
//
#include <hip/hip_runtime.h>
#include <hip/hip_bf16.h>
#include <stdint.h>

// Problem constants
// B=128 STREAM=512 IN_CH=4 EXTRA=5 GROUPS=2 DEPTH=3 STEP=16 LENGTH=32 RNN=256 OUT=10
// C=10 SIG_C=1110 W=31 F=2220, padded K = 2240, GEMM M = 31*128 = 3968, N = 768
// gi layout (f16, COALESCED): chunk u of thread gtid at step (t,bb):
//   f16 offset = ((t*8+bb)*6 + u)*2048 + gtid*4,  u = gs*2+gtc in [0,6)
// gi VALUES pre-scaled for exp2-based gate math:
//   r,z chunks: -log2e*(gemm + b_ih + b_hh);  n chunks: 2*log2e*(gemm + b_ih)
// GEMM (round 9): TLP fix. Round-5 fused PMC deconvolution: gemm phase ran at
//   18% occupancy (1.45 waves/SIMD), MfmaUtil ~7.6%, VALUBusy ~8%, HBM 0.4TB/s
//   -> 85% stall, latency-bound, NOT BW-bound. Every prior variant kept total
//   threads ~95k (1.45 waves/SIMD) -> all nulls. Now: 64x64 tiles -> 744 blocks
//   x 256 thr = 2.9 waves/SIMD (2x TLP). 48KB LDS -> 3 blocks/CU. Uniform
//   2 loads/wave/tile, 6 buffers, 5-deep, vmcnt(8) steady. Same K-accumulation
//   order -> gi bitwise identical.
// prep: unchanged (LDS-staged coalesced row store).
// GRU: unchanged (W_hh pinned in AGPRs, VGPR accumulators, exp2 gate math).

typedef _Float16 f16;
typedef f16  f16x2 __attribute__((ext_vector_type(2)));
typedef f16  f16x4 __attribute__((ext_vector_type(4)));
typedef f16  f16x8 __attribute__((ext_vector_type(8)));
typedef float f32x2 __attribute__((ext_vector_type(2)));
typedef float f32x4 __attribute__((ext_vector_type(4)));

#define ASYNC16(gp, lp) __builtin_amdgcn_global_load_lds( \
    (const __attribute__((address_space(1))) void*)(gp),  \
    (__attribute__((address_space(3))) void*)(lp), 16, 0, 0)

#define BAR_LDS() do { asm volatile("s_waitcnt lgkmcnt(0)" ::: "memory"); \
                       __builtin_amdgcn_s_barrier();                      \
                       asm volatile("" ::: "memory"); } while (0)

__device__ __forceinline__ float fexp2(float x) {
    float r; asm("v_exp_f32 %0, %1" : "=v"(r) : "v"(x)); return r;
}
__device__ __forceinline__ float frcp(float x) {
    float r; asm("v_rcp_f32 %0, %1" : "=v"(r) : "v"(x)); return r;
}

// ---------------------------------------------------------------- K0: prep
// blocks [0,840):    W_ih f32 -> f16 (pad 2220->2240), 8 elems/thread
// blocks [840,936):  W_hh f32 -> f16 (all) + fp8*16 (r,z rows), 8 elems/thread
// blocks [936,2920): signature chains, 4/block; LDS-staged coalesced row store
__global__ __launch_bounds__(256) void prep_kernel(const float* __restrict__ x,
                                                   const float* __restrict__ W_aug,
                                                   const float* __restrict__ Wih,
                                                   const float* __restrict__ Whh,
                                                   f16* __restrict__ sig16,
                                                   f16* __restrict__ wih16,
                                                   f16* __restrict__ whh16,
                                                   uint8_t* __restrict__ whh8) {
    __shared__ float dxs[4][31][10];
    __shared__ f16 srow[4][1112];                  // per-chain staging (1110 + pad)
    const int tid = threadIdx.x;
    if (blockIdx.x < 840) {
        int c = blockIdx.x * 256 + tid;          // chunk 0..215039
        int r = c / 280, kc = (c - r * 280) * 8;
        const float* src = Wih + (size_t)r * 2220 + kc;
        f16x8 o;
        if (kc + 8 <= 2220) {
            float4 v0 = *(const float4*)(src);
            float4 v1 = *(const float4*)(src + 4);
            o[0]=(f16)v0.x; o[1]=(f16)v0.y; o[2]=(f16)v0.z; o[3]=(f16)v0.w;
            o[4]=(f16)v1.x; o[5]=(f16)v1.y; o[6]=(f16)v1.z; o[7]=(f16)v1.w;
        } else {
#pragma unroll
            for (int j = 0; j < 8; j++)
                o[j] = (f16)((kc + j < 2220) ? src[j] : 0.0f);
        }
        *(f16x8*)(wih16 + (size_t)r * 2240 + kc) = o;
        return;
    }
    if (blockIdx.x < 936) {
        int c2 = ((int)blockIdx.x - 840) * 256 + tid;    // 0..24575
        int j8 = c2 * 8;
        float w[8];
        {
            float4 v0 = *(const float4*)(Whh + j8);
            float4 v1 = *(const float4*)(Whh + j8 + 4);
            w[0]=v0.x; w[1]=v0.y; w[2]=v0.z; w[3]=v0.w;
            w[4]=v1.x; w[5]=v1.y; w[6]=v1.z; w[7]=v1.w;
        }
        f16x8 o;
#pragma unroll
        for (int j = 0; j < 8; j++) o[j] = (f16)w[j];
        *(f16x8*)(whh16 + j8) = o;
        if (j8 < 131072) {                       // r,z gate rows -> fp8 e4m3 (x16)
            uint32_t p01 = (uint32_t)__builtin_amdgcn_cvt_pk_fp8_f32(w[0]*16.f, w[1]*16.f, 0, false) & 0xffffu;
            uint32_t p23 = (uint32_t)__builtin_amdgcn_cvt_pk_fp8_f32(w[2]*16.f, w[3]*16.f, 0, false) & 0xffffu;
            uint32_t p45 = (uint32_t)__builtin_amdgcn_cvt_pk_fp8_f32(w[4]*16.f, w[5]*16.f, 0, false) & 0xffffu;
            uint32_t p67 = (uint32_t)__builtin_amdgcn_cvt_pk_fp8_f32(w[6]*16.f, w[7]*16.f, 0, false) & 0xffffu;
            uint2 st = make_uint2(p01 | (p23 << 16), p45 | (p67 << 16));
            *(uint2*)(whh8 + j8) = st;
        }
        return;
    }
    // ---- signature chains (block-uniform branch; __syncthreads safe)
    const int sub = tid >> 6, t64 = tid & 63;
    const int cid = ((int)blockIdx.x - 936) * 4 + sub;   // 0..7935
    const int w = cid % 31;
    const int bg = cid / 31;
    const int b = bg >> 1, g = bg & 1;
    if (t64 < 31) {
        int s = w * 16 + t64;
        const float4 x0 = *(const float4*)(x + ((size_t)b * 512 + s) * 4);
        const float4 x1 = *(const float4*)(x + ((size_t)b * 512 + s + 1) * 4);
        float d0 = x1.x - x0.x, d1 = x1.y - x0.y, d2 = x1.z - x0.z, d3 = x1.w - x0.w;
        dxs[sub][t64][0] = d0; dxs[sub][t64][1] = d1;
        dxs[sub][t64][2] = d2; dxs[sub][t64][3] = d3;
        dxs[sub][t64][4] = 1.0f / 511.0f;
#pragma unroll
        for (int e = 0; e < 5; e++) {
            const float* wa = W_aug + (g * 5 + e) * 4;
            dxs[sub][t64][5 + e] = d0 * wa[0] + d1 * wa[1] + d2 * wa[2] + d3 * wa[3];
        }
    }
    __syncthreads();
    size_t base = ((size_t)(w * 128 + b)) * 2240 + (size_t)g * 1110;
    if (t64 < 50) {
        int p0 = 2 * t64, p1 = p0 + 1;
        int i0 = p0 / 10, j0 = p0 % 10, j1 = j0 + 1;   // p0 even -> j1 <= 9
        // loop-invariant LDS pointers: dynamic column index resolved ONCE
        const float* dz  = &dxs[sub][0][0];
        const float* pI  = dz + i0;
        const float* pJ0 = dz + j0;
        const float* pJ1 = dz + j1;
        float s3a[10], s3b[10];                        // constant-indexed -> registers
#pragma unroll
        for (int k = 0; k < 10; k++) { s3a[k] = 0.f; s3b[k] = 0.f; }
        float s2a = 0.f, s2b = 0.f, s1 = 0.f;
        for (int l = 0; l < 31; l++) {
            const float* row = dz + l * 10;
            float di  = pI[l * 10];
            float dj0 = pJ0[l * 10];
            float dj1 = pJ1[l * 10];
            float t0 = s1 + di * (1.0f / 3.0f);
            float a0 = s2a + t0 * (0.5f * dj0);
            float a1 = s2b + t0 * (0.5f * dj1);
#pragma unroll
            for (int k = 0; k < 10; k++) {
                float dk = row[k];
                s3a[k] += a0 * dk;
                s3b[k] += a1 * dk;
            }
            float u = s1 + 0.5f * di;
            s2a += u * dj0;
            s2b += u * dj1;
            s1 += di;
        }
        // stage into LDS (scatter is free there); global store happens coalesced below
        *(f16x2*)&srow[sub][10 + p0] = (f16x2){(f16)s2a, (f16)s2b};
#pragma unroll
        for (int k = 0; k < 5; k++)
            *(f16x2*)&srow[sub][110 + p0 * 10 + 2 * k] =
                (f16x2){(f16)s3a[2 * k], (f16)s3a[2 * k + 1]};
#pragma unroll
        for (int k = 0; k < 5; k++)
            *(f16x2*)&srow[sub][110 + p1 * 10 + 2 * k] =
                (f16x2){(f16)s3b[2 * k], (f16)s3b[2 * k + 1]};
    } else if (t64 < 60) {
        int c = t64 - 50;
        const float* pc = &dxs[sub][0][0] + c;
        float s = 0.f;
        for (int l = 0; l < 31; l++) s += pc[l * 10];
        srow[sub][c] = (f16)s;
    }
    __syncthreads();
    // coalesced copy-out: lane j writes 4B at base*2 + 4j (contiguous across lanes)
    for (int j = t64; j < 555; j += 64)
        *(f16x2*)(sig16 + base + 2 * j) = *(const f16x2*)&srow[sub][2 * j];
    if (g == 1 && t64 < 10)
        *(f16x2*)(sig16 + ((size_t)(w * 128 + b)) * 2240 + 2220 + 2 * t64) =
            (f16x2){(f16)0.0f, (f16)0.0f};
}

// ---------------------------------------------------------------- K2: gi = sig @ W_ih.T + biases (f16, coalesced GRU layout)
// 64x64 tile, 744 blocks (2.9 waves/SIMD), 4 waves, 6-buffer 5-deep pipeline.
__global__ __launch_bounds__(256) void gemm_kernel(const f16* __restrict__ A,     // 3968 x 2240
                                                   const f16* __restrict__ Bw,    // 768 x 2240 f16
                                                   const float* __restrict__ bias,
                                                   const float* __restrict__ bhh,
                                                   f16* __restrict__ Cgi) {
    const int lin = blockIdx.x;          // 744 = 62 mb x 12 nc
    const int nc = lin % 12;             // 64-col block
    const int mb = lin / 12;             // 0..61
    const int t = mb >> 1, half = mb & 1;
    __shared__ __align__(16) f16 As[6][64 * 32];    // 24 KB
    __shared__ __align__(16) f16 Bs[6][64 * 32];    // 24 KB (48 total -> 3 blocks/CU)
    const int tid = threadIdx.x, lane = tid & 63, wid = tid >> 6;   // wid 0..3
    const int l16 = lane & 15, quad = lane >> 4;
    const int lrow = lane >> 2, lk = lane & 3;
    const int Nbase = nc * 64;
    // per-wave staging: A rows [wid*16,+16), B rows [wid*16,+16)  (1 load each)
    const f16* gaA = A  + (size_t)(mb * 64 + wid * 16 + lrow) * 2240 + lk * 8;
    const f16* gbB = Bw + (size_t)(Nbase + wid * 16 + lrow) * 2240 + lk * 8;

#define GISSUE(KT, BUF) do { \
        int _k0 = (KT) * 32; \
        ASYNC16(gaA + _k0, &As[BUF][(wid * 16) * 32]); \
        ASYNC16(gbB + _k0, &Bs[BUF][(wid * 16) * 32]); } while (0)

#define GCOMPUTE(BUF) do { \
        f16x8 af, bf[4]; \
        af = *(const f16x8*)&As[BUF][(wid * 16 + l16) * 32 + quad * 8]; \
        _Pragma("unroll") \
        for (int nt = 0; nt < 4; nt++) \
            bf[nt] = *(const f16x8*)&Bs[BUF][(nt * 16 + l16) * 32 + quad * 8]; \
        _Pragma("unroll") \
        for (int nt = 0; nt < 4; nt++) \
            acc[nt] = __builtin_amdgcn_mfma_f32_16x16x32_f16(af, bf[nt], acc[nt], 0, 0, 0); } while (0)

    f32x4 acc[4];
#pragma unroll
    for (int nt = 0; nt < 4; nt++) acc[nt] = (f32x4){0.f, 0.f, 0.f, 0.f};

    // prologue: 5 tiles in flight (10 loads per wave)
    GISSUE(0, 0); GISSUE(1, 1); GISSUE(2, 2); GISSUE(3, 3); GISSUE(4, 4);
    for (int kt = 0; kt < 65; kt++) {
        // per-wave: wait tile kt (oldest 2 of 10); 4 tiles stay in flight
        asm volatile("s_waitcnt vmcnt(8) lgkmcnt(0)\n\ts_barrier" ::: "memory");
        GISSUE(kt + 5, (kt + 5) % 6);
        GCOMPUTE(kt % 6);
    }
    // graded drain: tiles 65..69 (outstanding 10,8,6,4,2 loads at entry)
    asm volatile("s_waitcnt vmcnt(8) lgkmcnt(0)\n\ts_barrier" ::: "memory");
    GCOMPUTE(5);
    asm volatile("s_waitcnt vmcnt(6) lgkmcnt(0)\n\ts_barrier" ::: "memory");
    GCOMPUTE(0);
    asm volatile("s_waitcnt vmcnt(4) lgkmcnt(0)\n\ts_barrier" ::: "memory");
    GCOMPUTE(1);
    asm volatile("s_waitcnt vmcnt(2) lgkmcnt(0)\n\ts_barrier" ::: "memory");
    GCOMPUTE(2);
    asm volatile("s_waitcnt vmcnt(0) lgkmcnt(0)\n\ts_barrier" ::: "memory");
    GCOMPUTE(3);

    // epilogue: coalesced chunk layout + exp2 pre-scaling
    const float NEG_LOG2E = -1.4426950408889634f;
    const float TWO_LOG2E =  2.8853900817779268f;
    const int bbv = half * 4 + wid;     // (row%128)/16 for this wave's 16 rows
#pragma unroll
    for (int nt = 0; nt < 4; nt++) {
        int col = Nbase + nt * 16 + l16;
        float bvv = bias[col] + (col < 512 ? bhh[col] : 0.0f);   // fold b_hh into r,z
        float scl = (col < 512) ? NEG_LOG2E : TWO_LOG2E;
        int gs = col >> 8, hcc = col & 255;
        int gw = hcc >> 5, gtc = (hcc >> 4) & 1, gl = hcc & 15;
        int u = gs * 2 + gtc;
        int gtid = gw * 64 + quad * 16 + gl;
        size_t off = ((size_t)((t * 8 + bbv) * 6 + u)) * 2048 + (size_t)gtid * 4;
        f16x4 st;
#pragma unroll
        for (int rr = 0; rr < 4; rr++) st[rr] = (f16)((acc[nt][rr] + bvv) * scl);
        *(f16x4*)(Cgi + off) = st;
    }
#undef GISSUE
#undef GCOMPUTE
}

// ---------------------------------------------------------------- K3: GRU scan
// W_hh fragments pinned a[0:127]; accumulators in VGPRs (unified file).
#define ACLOB \
  "a0","a1","a2","a3","a4","a5","a6","a7","a8","a9","a10","a11","a12","a13","a14","a15", \
  "a16","a17","a18","a19","a20","a21","a22","a23","a24","a25","a26","a27","a28","a29","a30","a31", \
  "a32","a33","a34","a35","a36","a37","a38","a39","a40","a41","a42","a43","a44","a45","a46","a47", \
  "a48","a49","a50","a51","a52","a53","a54","a55","a56","a57","a58","a59","a60","a61","a62","a63", \
  "a64","a65","a66","a67","a68","a69","a70","a71","a72","a73","a74","a75","a76","a77","a78","a79", \
  "a80","a81","a82","a83","a84","a85","a86","a87","a88","a89","a90","a91","a92","a93","a94","a95", \
  "a96","a97","a98","a99","a100","a101","a102","a103","a104","a105","a106","a107","a108","a109","a110","a111", \
  "a112","a113","a114","a115","a116","a117","a118","a119","a120","a121","a122","a123","a124","a125","a126","a127"

#define LF8(A0,A1, U, KT) do { \
  f32x2 _t = *(const f32x2*)(whh8 + (size_t)(((U) >> 1) * 256 + wid * 32 + ((U) & 1) * 16 + l16) * 256 + (KT) * 32 + quad * 8); \
  asm volatile("v_accvgpr_write_b32 a" #A0 ", %0\n\t" \
               "v_accvgpr_write_b32 a" #A1 ", %1" \
               :: "v"(_t[0]), "v"(_t[1]) : "a" #A0, "a" #A1); } while (0)

#define LFN(A0,A1,A2,A3, TC, KT) do { \
  f32x4 _t = *(const f32x4*)(whh16 + (size_t)(512 + wid * 32 + (TC) * 16 + l16) * 256 + (KT) * 32 + quad * 8); \
  asm volatile("v_accvgpr_write_b32 a" #A0 ", %0\n\t" \
               "v_accvgpr_write_b32 a" #A1 ", %1\n\t" \
               "v_accvgpr_write_b32 a" #A2 ", %2\n\t" \
               "v_accvgpr_write_b32 a" #A3 ", %3" \
               :: "v"(_t[0]), "v"(_t[1]), "v"(_t[2]), "v"(_t[3]) \
               : "a" #A0, "a" #A1, "a" #A2, "a" #A3); } while (0)

// fp8 gate MFMA groups: accumulators %[aR0],%[aR1],%[aZ0],%[aZ1] (VGPR quads)
#define FP8GZ(P, F0,F1,F2,F3) \
  "v_mfma_f32_16x16x32_fp8_fp8 %[aR0], " P ", a[" F0 "], %[zq]\n\t" \
  "v_mfma_f32_16x16x32_fp8_fp8 %[aR1], " P ", a[" F1 "], %[zq]\n\t" \
  "v_mfma_f32_16x16x32_fp8_fp8 %[aZ0], " P ", a[" F2 "], %[zq]\n\t" \
  "v_mfma_f32_16x16x32_fp8_fp8 %[aZ1], " P ", a[" F3 "], %[zq]\n\t"

#define FP8G(P, F0,F1,F2,F3) \
  "v_mfma_f32_16x16x32_fp8_fp8 %[aR0], " P ", a[" F0 "], %[aR0]\n\t" \
  "v_mfma_f32_16x16x32_fp8_fp8 %[aR1], " P ", a[" F1 "], %[aR1]\n\t" \
  "v_mfma_f32_16x16x32_fp8_fp8 %[aZ0], " P ", a[" F2 "], %[aZ0]\n\t" \
  "v_mfma_f32_16x16x32_fp8_fp8 %[aZ1], " P ", a[" F3 "], %[aZ1]\n\t"

#define F16GZ(Q, G0,G1) \
  "v_mfma_f32_16x16x32_f16 %[aN0], " Q ", a[" G0 "], %[zq]\n\t" \
  "v_mfma_f32_16x16x32_f16 %[aN1], " Q ", a[" G1 "], %[zq]\n\t"

#define F16G(Q, G0,G1) \
  "v_mfma_f32_16x16x32_f16 %[aN0], " Q ", a[" G0 "], %[aN0]\n\t" \
  "v_mfma_f32_16x16x32_f16 %[aN1], " Q ", a[" G1 "], %[aN1]\n\t"

__global__ __launch_bounds__(512, 2) void gru_kernel(const f16* __restrict__ gi,
                                                     const f16* __restrict__ whh16,
                                                     const uint8_t* __restrict__ whh8,
                                                     const float* __restrict__ b_hh,
                                                     const float* __restrict__ W_out,
                                                     const float* __restrict__ b_out,
                                                     float* __restrict__ out) {
    __shared__ __align__(16) f16 hbufF[2][16 * 280];      // f16 h (n-gate A + head)
    __shared__ __align__(16) uint8_t hbuf8[2][16 * 272];  // fp8 h (rz A)
    const int tid = threadIdx.x, lane = tid & 63, wid = tid >> 6;   // wid 0..7
    const int quad = lane >> 4, l16 = lane & 15;
    const int bb = blockIdx.x;

    for (int i = tid; i < 16 * 280; i += 512) hbufF[1][i] = (f16)0.0f;
    for (int i = tid; i < 16 * 272; i += 512) hbuf8[1][i] = 0;

    LF8(0,1, 0,0);   LF8(2,3, 0,1);   LF8(4,5, 0,2);   LF8(6,7, 0,3);
    LF8(8,9, 0,4);   LF8(10,11, 0,5); LF8(12,13, 0,6); LF8(14,15, 0,7);
    LF8(16,17, 1,0); LF8(18,19, 1,1); LF8(20,21, 1,2); LF8(22,23, 1,3);
    LF8(24,25, 1,4); LF8(26,27, 1,5); LF8(28,29, 1,6); LF8(30,31, 1,7);
    LF8(32,33, 2,0); LF8(34,35, 2,1); LF8(36,37, 2,2); LF8(38,39, 2,3);
    LF8(40,41, 2,4); LF8(42,43, 2,5); LF8(44,45, 2,6); LF8(46,47, 2,7);
    LF8(48,49, 3,0); LF8(50,51, 3,1); LF8(52,53, 3,2); LF8(54,55, 3,3);
    LF8(56,57, 3,4); LF8(58,59, 3,5); LF8(60,61, 3,6); LF8(62,63, 3,7);
    LFN(64,65,66,67,   0,0); LFN(68,69,70,71,   0,1); LFN(72,73,74,75,   0,2); LFN(76,77,78,79,   0,3);
    LFN(80,81,82,83,   0,4); LFN(84,85,86,87,   0,5); LFN(88,89,90,91,   0,6); LFN(92,93,94,95,   0,7);
    LFN(96,97,98,99,   1,0); LFN(100,101,102,103, 1,1); LFN(104,105,106,107, 1,2); LFN(108,109,110,111, 1,3);
    LFN(112,113,114,115, 1,4); LFN(116,117,118,119, 1,5); LFN(120,121,122,123, 1,6); LFN(124,125,126,127, 1,7);

    const float C2 = 2.8853900817779268f;   // 2*log2e
    float bhn[2];
#pragma unroll
    for (int tc = 0; tc < 2; tc++) bhn[tc] = C2 * b_hh[512 + wid * 32 + tc * 16 + l16];
    float hm[2][4];
#pragma unroll
    for (int tc = 0; tc < 2; tc++)
#pragma unroll
        for (int rr = 0; rr < 4; rr++) hm[tc][rr] = 0.f;

    uint32_t aF0 = (uint32_t)(uintptr_t)(__attribute__((address_space(3))) const void*)
                       (&hbufF[0][l16 * 280 + quad * 8]);
    uint32_t aF1 = (uint32_t)(uintptr_t)(__attribute__((address_space(3))) const void*)
                       (&hbufF[1][l16 * 280 + quad * 8]);
    uint32_t a80 = (uint32_t)(uintptr_t)(__attribute__((address_space(3))) const void*)
                       (&hbuf8[0][l16 * 272 + quad * 8]);
    uint32_t a81 = (uint32_t)(uintptr_t)(__attribute__((address_space(3))) const void*)
                       (&hbuf8[1][l16 * 272 + quad * 8]);

    // coalesced gi: per (t,bb) slab = 12288 f16; chunk u at u*2048; thread at tid*4
    const size_t lanebase = (size_t)bb * 12288 + (size_t)tid * 4;
    f16x4 gcur[6];
#pragma unroll
    for (int u = 0; u < 6; u++)
        gcur[u] = *(const f16x4*)(gi + lanebase + u * 2048);

    const f32x4 zq = (f32x4){0.f, 0.f, 0.f, 0.f};

    BAR_LDS();

    for (int t = 0; t < 31; t++) {
        const uint32_t a8 = (t & 1) ? a80 : a81;
        const uint32_t aF = (t & 1) ? aF0 : aF1;
        f32x4 aR0, aR1, aZ0, aZ1, aN0, aN1;
        f32x2 p0, p1, p2;
        f32x4 q0, q1, q2;
        asm volatile(
            "s_setprio 1\n\t"
            "ds_read_b64  %[p0], %[a8] offset:0\n\t"
            "ds_read_b128 %[q0], %[aF] offset:0\n\t"
            "ds_read_b64  %[p1], %[a8] offset:32\n\t"
            "ds_read_b128 %[q1], %[aF] offset:64\n\t"
            "ds_read_b64  %[p2], %[a8] offset:64\n\t"
            "ds_read_b128 %[q2], %[aF] offset:128\n\t"
            "s_waitcnt lgkmcnt(5)\n\t"
            FP8GZ("%[p0]", "0:1","16:17","32:33","48:49")
            "ds_read_b64  %[p0], %[a8] offset:96\n\t"
            "s_waitcnt lgkmcnt(5)\n\t"
            F16GZ("%[q0]", "64:67","96:99")
            "ds_read_b128 %[q0], %[aF] offset:192\n\t"
            "s_waitcnt lgkmcnt(5)\n\t"
            FP8G("%[p1]", "2:3","18:19","34:35","50:51")
            "ds_read_b64  %[p1], %[a8] offset:128\n\t"
            "s_waitcnt lgkmcnt(5)\n\t"
            F16G("%[q1]", "68:71","100:103")
            "ds_read_b128 %[q1], %[aF] offset:256\n\t"
            "s_waitcnt lgkmcnt(5)\n\t"
            FP8G("%[p2]", "4:5","20:21","36:37","52:53")
            "ds_read_b64  %[p2], %[a8] offset:160\n\t"
            "s_waitcnt lgkmcnt(5)\n\t"
            F16G("%[q2]", "72:75","104:107")
            "ds_read_b128 %[q2], %[aF] offset:320\n\t"
            "s_waitcnt lgkmcnt(5)\n\t"
            FP8G("%[p0]", "6:7","22:23","38:39","54:55")
            "ds_read_b64  %[p0], %[a8] offset:192\n\t"
            "s_waitcnt lgkmcnt(5)\n\t"
            F16G("%[q0]", "76:79","108:111")
            "ds_read_b128 %[q0], %[aF] offset:384\n\t"
            "s_waitcnt lgkmcnt(5)\n\t"
            FP8G("%[p1]", "8:9","24:25","40:41","56:57")
            "ds_read_b64  %[p1], %[a8] offset:224\n\t"
            "s_waitcnt lgkmcnt(5)\n\t"
            F16G("%[q1]", "80:83","112:115")
            "ds_read_b128 %[q1], %[aF] offset:448\n\t"
            "s_waitcnt lgkmcnt(5)\n\t"
            FP8G("%[p2]", "10:11","26:27","42:43","58:59")
            "s_waitcnt lgkmcnt(4)\n\t"
            F16G("%[q2]", "84:87","116:119")
            "s_waitcnt lgkmcnt(3)\n\t"
            FP8G("%[p0]", "12:13","28:29","44:45","60:61")
            "s_waitcnt lgkmcnt(2)\n\t"
            F16G("%[q0]", "88:91","120:123")
            "s_waitcnt lgkmcnt(1)\n\t"
            FP8G("%[p1]", "14:15","30:31","46:47","62:63")
            "s_waitcnt lgkmcnt(0)\n\t"
            F16G("%[q1]", "92:95","124:127")
            "s_setprio 0\n\t"
            "s_nop 7\n\ts_nop 7"
            : [aR0]"=&v"(aR0), [aR1]"=&v"(aR1), [aZ0]"=&v"(aZ0), [aZ1]"=&v"(aZ1),
              [aN0]"=&v"(aN0), [aN1]"=&v"(aN1),
              [p0]"=&v"(p0), [p1]"=&v"(p1), [p2]"=&v"(p2),
              [q0]"=&v"(q0), [q1]"=&v"(q1), [q2]"=&v"(q2)
            : [a8]"v"(a8), [aF]"v"(aF), [zq]"v"(zq)
            : ACLOB);

        // gate math (exp2 form): accR/accZ are rz matmul (x1/16), accN is n matmul
        f16* hdF = hbufF[t & 1];
        uint8_t* hd8 = hbuf8[t & 1];
        const float C1N16 = -0.09016844005556021f;   // -log2e/16
#pragma unroll
        for (int tc = 0; tc < 2; tc++) {
            const int hcx = wid * 32 + tc * 16 + l16;
            const f32x4 vR = tc ? aR1 : aR0;
            const f32x4 vZ = tc ? aZ1 : aZ0;
            const f32x4 vN = tc ? aN1 : aN0;
#pragma unroll
            for (int rr = 0; rr < 4; rr++) {
                float rg = frcp(1.f + fexp2(fmaf(C1N16, vR[rr], (float)gcur[tc][rr])));
                float zg = frcp(1.f + fexp2(fmaf(C1N16, vZ[rr], (float)gcur[2 + tc][rr])));
                float t2 = fmaf(rg, fmaf(C2, vN[rr], bhn[tc]), (float)gcur[4 + tc][rr]);
                float e2 = fexp2(t2);
                float ng = fmaf(-2.f, frcp(e2 + 1.f), 1.f);   // tanh
                float h  = fmaf(zg, hm[tc][rr] - ng, ng);     // (1-z)n + z*h
                hm[tc][rr] = h;
                hdF[(quad * 4 + rr) * 280 + hcx] = (f16)h;
                int pk = __builtin_amdgcn_cvt_pk_fp8_f32(h, h, 0, false);
                hd8[(quad * 4 + rr) * 272 + hcx] = (uint8_t)pk;
            }
        }
        // prefetch gi for t+1 (registers; survives lgkm-only barrier)
        {
            int tn = (t < 30) ? t + 1 : 30;
            const f16* gsrc = gi + (size_t)tn * 98304 + lanebase;
#pragma unroll
            for (int u = 0; u < 6; u++)
                gcur[u] = *(const f16x4*)(gsrc + u * 2048);
        }
        BAR_LDS();
    }
    // output head: final h in hbufF[0]
    if (tid < 160) {
        int r = tid / 10, oc = tid - r * 10;
        const f16* hfin = hbufF[0];
        float s = b_out[oc];
        for (int k = 0; k < 256; k++) s += (float)hfin[r * 280 + k] * W_out[oc * 256 + k];
        out[(bb * 16 + r) * 10 + oc] = frcp(1.f + __expf(-s));
    }
}

// ---------------------------------------------------------------- launch
extern "C" void kernel_launch(void* const* d_in, const int* in_sizes, int n_in,
                              void* d_out, int out_size, void* d_ws, size_t ws_size,
                              hipStream_t stream) {
    const float* x     = (const float*)d_in[0];
    const float* W_aug = (const float*)d_in[1];
    // d_in[2] = b_aug — cancels in dx, unused
    const float* W_ih  = (const float*)d_in[3];
    const float* W_hh  = (const float*)d_in[4];
    const float* b_ih  = (const float*)d_in[5];
    const float* b_hh  = (const float*)d_in[6];
    const float* W_out = (const float*)d_in[7];
    const float* b_out = (const float*)d_in[8];
    float* out = (float*)d_out;

    char* ws = (char*)d_ws;
    const size_t SIG_BYTES  = (size_t)3968 * 2240 * 2;           // 17,776,640
    const size_t WIH_BYTES  = (size_t)768 * 2240 * 2;            //  3,440,640
    const size_t WHH_BYTES  = (size_t)768 * 256 * 2;             //    393,216
    const size_t WHH8_BYTES = (size_t)512 * 256;                 //    131,072
    const size_t GI_BYTES   = (size_t)31 * 8 * 6 * 512 * 4 * 2;  //  6,094,848
    if (ws_size < SIG_BYTES + WIH_BYTES + WHH_BYTES + WHH8_BYTES + GI_BYTES) return;
    f16* sig16    = (f16*)ws;
    f16* wih16    = (f16*)(ws + SIG_BYTES);
    f16* whh16    = (f16*)(ws + SIG_BYTES + WIH_BYTES);
    uint8_t* whh8 = (uint8_t*)(ws + SIG_BYTES + WIH_BYTES + WHH_BYTES);
    f16* giw      = (f16*)(ws + SIG_BYTES + WIH_BYTES + WHH_BYTES + WHH8_BYTES);

    hipLaunchKernelGGL(prep_kernel, dim3(2920), dim3(256), 0, stream,
                       x, W_aug, W_ih, W_hh, sig16, wih16, whh16, whh8);
    hipLaunchKernelGGL(gemm_kernel, dim3(744), dim3(256), 0, stream,
                       sig16, wih16, b_ih, b_hh, giw);
    hipLaunchKernelGGL(gru_kernel, dim3(8), dim3(512), 0, stream,
                       giw, whh16, whh8, b_hh, W_out, b_out, out);
}